// Round 12
// baseline (427.179 us; speedup 1.0000x reference)
//
#include <hip/hip_runtime.h>
#include <cstdio>

#define E_DIM 512
#define L_DIM 4096
#define B_DIM 8
#define H_DIM 8
#define T_DIM 2
#define M_ROWS 32768

typedef __attribute__((ext_vector_type(8))) __bf16 bf16x8;
typedef __attribute__((ext_vector_type(4))) float f32x4;

static __device__ __forceinline__ unsigned short f2bf(float f) {
  unsigned int u = __float_as_uint(f);
  return (unsigned short)((u + 0x7FFFu + ((u >> 16) & 1u)) >> 16);
}
static __device__ __forceinline__ unsigned int pkbf(float lo, float hi) {
  return (unsigned int)f2bf(lo) | ((unsigned int)f2bf(hi) << 16);
}
static __device__ __forceinline__ float bf2f(unsigned short u) {
  return __uint_as_float((unsigned int)u << 16);
}
static __device__ __forceinline__ void unpk8(uint4 u, float* f) {
  f[0] = bf2f((unsigned short)u.x); f[1] = bf2f((unsigned short)(u.x >> 16));
  f[2] = bf2f((unsigned short)u.y); f[3] = bf2f((unsigned short)(u.y >> 16));
  f[4] = bf2f((unsigned short)u.z); f[5] = bf2f((unsigned short)(u.z >> 16));
  f[6] = bf2f((unsigned short)u.w); f[7] = bf2f((unsigned short)(u.w >> 16));
}
// XOR swizzle at 8-elem (16B) granules
static __device__ __forceinline__ int swz64(int row, int e) {
  return row * 64 + ((((e >> 3) ^ row) & 7) << 3) + (e & 7);
}
static __device__ __forceinline__ int swz128(int row, int e) {
  return row * 128 + ((((e >> 3) ^ row) & 7) << 3) + ((e >> 3) & 8) * 8 + (e & 7);
}
// async global->LDS, 16B per lane; LDS dest = wave-uniform base + lane*16
static __device__ __forceinline__ void gl_lds16(const unsigned short* g,
                                                unsigned short* l) {
  __builtin_amdgcn_global_load_lds(
      (const __attribute__((address_space(1))) unsigned int*)g,
      (__attribute__((address_space(3))) unsigned int*)l, 16, 0, 0);
}

// ---------------------------------------------------------------------------
__global__ void sincos_kernel(float* __restrict__ sintab, float* __restrict__ costab) {
  int i = blockIdx.x * blockDim.x + threadIdx.x;
  if (i < L_DIM) {
    float idx = 1.57079632679489662f * (float)(i + 1) / (float)L_DIM;
    sintab[i] = sinf(idx);
    costab[i] = cosf(idx);
  }
}

__global__ void convf2b(const float* __restrict__ src, unsigned short* __restrict__ dst,
                        int n8) {
  for (int i = blockIdx.x * blockDim.x + threadIdx.x; i < n8; i += gridDim.x * blockDim.x) {
    float4 a = *(const float4*)(src + (size_t)i * 8);
    float4 b = *(const float4*)(src + (size_t)i * 8 + 4);
    uint4 o;
    o.x = pkbf(a.x, a.y); o.y = pkbf(a.z, a.w);
    o.z = pkbf(b.x, b.y); o.w = pkbf(b.z, b.w);
    *(uint4*)(dst + (size_t)i * 8) = o;
  }
}

// ---------------------------------------------------------------------------
// Y[M][N] = X[M][512] @ W[N][512]^T + bias[N]; N = 512<<(NBL2-2).
// AF32: A is fp32 in global; staged via issue-early (8x float4 -> regs before
//       MFMA block) / write-late (convert + swizzled ds_write after MFMA) —
//       T14 split, kills the separate convf2b pass. B always bf16 gl_lds.
// MODE 0: plain bf16 store | MODE 1: fp32 store | MODE 2: u=exp(acc+bias)
// bf16 store + per-mtile column sums -> psum (K path).
// ---------------------------------------------------------------------------
#define YHALF 16777216
template <bool AF32, int MODE, int NBL2>
__global__ __launch_bounds__(256, 2) void gemm_xwt(
    const void* __restrict__ Xv, const unsigned short* __restrict__ W,
    const float* __restrict__ bias, void* __restrict__ Yv,
    float* __restrict__ psum) {
  __shared__ __align__(16) unsigned short smem[32768];  // 2 x (As 8192 + Bs 8192)
  __shared__ float sf2[256];
  const int tid = threadIdx.x;
  const int id = blockIdx.x;
  const int j = id >> 3;
  const int mb = (id & 7) * 32 + (j >> NBL2);
  const int nb = j & ((1 << NBL2) - 1);
  const int m0 = mb * 128, n0 = nb * 128;
  const int lane = tid & 63;
  const int w = tid >> 6;
  const int wr = w >> 1, wc = w & 1;
  const int lr = lane & 15;
  const int lk = (lane >> 4) * 8;
  const int rq = lane >> 4;
  const int srow = lane >> 3;                 // 0..7
  const int gsrc8 = ((lane & 7) ^ srow) * 8;  // inverse-swizzled source granule
  // A-f32 staging geometry: thread covers row tid>>1, col-half tid&1
  const int ar = tid >> 1;
  const int ah = tid & 1;
  float4 a4[8];
  f32x4 acc[4][4];
#pragma unroll
  for (int i = 0; i < 4; ++i)
#pragma unroll
    for (int jj = 0; jj < 4; ++jj) acc[i][jj] = (f32x4){0.f, 0.f, 0.f, 0.f};

  // prologue: stage tile 0 into buffer 0
  if (AF32) {
    const float* Xf = (const float*)Xv;
#pragma unroll
    for (int i = 0; i < 8; ++i)
      a4[i] = *(const float4*)(Xf + (size_t)(m0 + ar) * 512 + ah * 32 + i * 4);
#pragma unroll
    for (int i = 0; i < 4; ++i) {
      int rb = w * 32 + i * 8;
      gl_lds16(W + (size_t)(n0 + rb + srow) * 512 + gsrc8, &smem[8192 + rb * 64]);
    }
#pragma unroll
    for (int q = 0; q < 4; ++q) {
      uint4 o;
      o.x = pkbf(a4[q * 2].x, a4[q * 2].y);
      o.y = pkbf(a4[q * 2].z, a4[q * 2].w);
      o.z = pkbf(a4[q * 2 + 1].x, a4[q * 2 + 1].y);
      o.w = pkbf(a4[q * 2 + 1].z, a4[q * 2 + 1].w);
      int g = ah * 4 + q;
      *(uint4*)&smem[ar * 64 + (((g ^ ar) & 7) << 3)] = o;
    }
  } else {
    const unsigned short* Xb = (const unsigned short*)Xv;
#pragma unroll
    for (int i = 0; i < 4; ++i) {
      int rb = w * 32 + i * 8;
      gl_lds16(Xb + (size_t)(m0 + rb + srow) * 512 + gsrc8, &smem[rb * 64]);
      gl_lds16(W + (size_t)(n0 + rb + srow) * 512 + gsrc8, &smem[8192 + rb * 64]);
    }
  }
  __syncthreads();

#pragma unroll
  for (int step = 0; step < 8; ++step) {
    const int cur = step & 1;
    if (step < 7) {
      unsigned short* Ab = smem + (cur ^ 1) * 16384;
      const int kn = (step + 1) * 64;
      if (AF32) {
        const float* Xf = (const float*)Xv;
#pragma unroll
        for (int i = 0; i < 8; ++i)
          a4[i] = *(const float4*)(Xf + (size_t)(m0 + ar) * 512 + kn + ah * 32 + i * 4);
#pragma unroll
        for (int i = 0; i < 4; ++i) {
          int rb = w * 32 + i * 8;
          gl_lds16(W + (size_t)(n0 + rb + srow) * 512 + kn + gsrc8,
                   &Ab[8192 + rb * 64]);
        }
      } else {
        const unsigned short* Xb = (const unsigned short*)Xv;
#pragma unroll
        for (int i = 0; i < 4; ++i) {
          int rb = w * 32 + i * 8;
          gl_lds16(Xb + (size_t)(m0 + rb + srow) * 512 + kn + gsrc8, &Ab[rb * 64]);
          gl_lds16(W + (size_t)(n0 + rb + srow) * 512 + kn + gsrc8,
                   &Ab[8192 + rb * 64]);
        }
      }
    }
    const unsigned short* As = smem + cur * 16384;
    const unsigned short* Bs = As + 8192;
#pragma unroll
    for (int kk = 0; kk < 2; ++kk) {
      bf16x8 av[4], bv[4];
      int ke = kk * 32 + lk;
#pragma unroll
      for (int fm = 0; fm < 4; ++fm)
        av[fm] = *(const bf16x8*)&As[swz64(wr * 64 + fm * 16 + lr, ke)];
#pragma unroll
      for (int fn = 0; fn < 4; ++fn)
        bv[fn] = *(const bf16x8*)&Bs[swz64(wc * 64 + fn * 16 + lr, ke)];
#pragma unroll
      for (int fm = 0; fm < 4; ++fm)
#pragma unroll
        for (int fn = 0; fn < 4; ++fn)
          acc[fm][fn] = __builtin_amdgcn_mfma_f32_16x16x32_bf16(av[fm], bv[fn],
                                                                acc[fm][fn], 0, 0, 0);
    }
    if (AF32 && step < 7) {
      // write-late: convert held A regs into buf^1 (swizzled)
      unsigned short* Ab = smem + (cur ^ 1) * 16384;
#pragma unroll
      for (int q = 0; q < 4; ++q) {
        uint4 o;
        o.x = pkbf(a4[q * 2].x, a4[q * 2].y);
        o.y = pkbf(a4[q * 2].z, a4[q * 2].w);
        o.z = pkbf(a4[q * 2 + 1].x, a4[q * 2 + 1].y);
        o.w = pkbf(a4[q * 2 + 1].z, a4[q * 2 + 1].w);
        int g = ah * 4 + q;
        *(uint4*)&Ab[ar * 64 + (((g ^ ar) & 7) << 3)] = o;
      }
    }
    __syncthreads();  // drains ds_write (lgkm) + gl_lds (vm) + this tile's reads
  }

  // ---- epilogues ----
  if (MODE == 0 || MODE == 2) {
    unsigned short* Cs = smem;  // 128 x (stride 136) bf16 tile
    if (MODE == 0) {
#pragma unroll
      for (int fn = 0; fn < 4; ++fn) {
        int col = wc * 64 + fn * 16 + lr;
        float bb = bias[n0 + col];
#pragma unroll
        for (int fm = 0; fm < 4; ++fm) {
          int row = wr * 64 + fm * 16 + rq * 4;
#pragma unroll
          for (int jj = 0; jj < 4; ++jj)
            Cs[(row + jj) * 136 + col] = f2bf(acc[fm][fn][jj] + bb);
        }
      }
    } else {
      // MODE 2: u = exp(logit); per-column sums over this tile's 128 rows
#pragma unroll
      for (int fn = 0; fn < 4; ++fn) {
        int col = wc * 64 + fn * 16 + lr;
        float bb = bias[n0 + col];
        float S = 0.f;
#pragma unroll
        for (int fm = 0; fm < 4; ++fm) {
          int row = wr * 64 + fm * 16 + rq * 4;
#pragma unroll
          for (int jj = 0; jj < 4; ++jj) {
            float u = __expf(acc[fm][fn][jj] + bb);
            S += u;
            Cs[(row + jj) * 136 + col] = f2bf(u);
          }
        }
        S += __shfl_xor(S, 16);
        S += __shfl_xor(S, 32);
        if (rq == 0) sf2[wr * 128 + col] = S;
      }
    }
    __syncthreads();
    if (MODE == 2 && tid < 128) {
      float S = sf2[tid] + sf2[128 + tid];
      psum[(size_t)(m0 >> 7) * (128 << NBL2) + n0 + tid] = S;
    }
    unsigned short* Yb = (unsigned short*)Yv + (size_t)(n0 >> 9) * YHALF;
    const int nc = n0 & 511;
#pragma unroll
    for (int i = 0; i < 8; ++i) {
      int idx = tid + i * 256;     // 0..2047
      int row = idx >> 4, g = idx & 15;
      *(uint4*)(Yb + (size_t)(m0 + row) * 512 + nc + g * 8) =
          *(const uint4*)&Cs[row * 136 + g * 8];
    }
  } else {  // MODE 1: fp32 store
    float* Cf = (float*)smem;  // 64 x (stride 132)
    float* Yf = (float*)Yv;
#pragma unroll
    for (int p = 0; p < 2; ++p) {
      if (p) __syncthreads();
      if (wr == p) {
#pragma unroll
        for (int fn = 0; fn < 4; ++fn) {
          int col = wc * 64 + fn * 16 + lr;
          float bb = bias[n0 + col];
#pragma unroll
          for (int fm = 0; fm < 4; ++fm) {
            int lrow = fm * 16 + rq * 4;
#pragma unroll
            for (int jj = 0; jj < 4; ++jj)
              Cf[(lrow + jj) * 132 + col] = acc[fm][fn][jj] + bb;
          }
        }
      }
      __syncthreads();
#pragma unroll
      for (int i = 0; i < 8; ++i) {
        int idx = tid + i * 256;
        int row = idx >> 5, g = idx & 31;
        *(float4*)(Yf + (size_t)(m0 + p * 64 + row) * 512 + n0 + g * 4) =
            *(const float4*)&Cf[row * 132 + g * 4];
      }
    }
  }
}

// ---------------------------------------------------------------------------
// column-sum reduce over the 32 mtiles of each b -> 1/S ; coloff selects term
// ---------------------------------------------------------------------------
__global__ void colsum_reduce(const float* __restrict__ psum,
                              float* __restrict__ colinv, int coloff) {
  int i = blockIdx.x * 256 + threadIdx.x;  // b*512+f, 0..4095
  int b = i >> 9, f = i & 511;
  float S = 0.f;
#pragma unroll
  for (int c = 0; c < 32; ++c)
    S += psum[(size_t)(b * 32 + c) * 1024 + coloff + f];
  colinv[i] = 1.f / S;
}

// ---------------------------------------------------------------------------
// kv partials via MFMA: C[d][ncol] = sum_s u[s][d]*B[s][ncol], B=[v*sin|v*cos]
// ---------------------------------------------------------------------------
__global__ __launch_bounds__(256) void kv_mfma(
    const unsigned short* __restrict__ Up, const unsigned short* __restrict__ Vpb,
    const float* __restrict__ sintab, const float* __restrict__ costab,
    float* __restrict__ kvpart) {
  __shared__ __align__(16) unsigned short kT[64 * 64];
  __shared__ __align__(16) unsigned short vT[128 * 64];
  const int tid = threadIdx.x;
  const int chunk = blockIdx.x;
  const int n = blockIdx.y;
  const int b = n >> 3, h = n & 7;
  const int lane = tid & 63;
  const int w = tid >> 6;
  const int lr = lane & 15;
  const int lk = (lane >> 4) * 8;
  const int sp = tid & 31;
  const int g = tid >> 5;
  f32x4 acc[4][2];
#pragma unroll
  for (int i = 0; i < 4; ++i) {
    acc[i][0] = (f32x4){0.f, 0.f, 0.f, 0.f};
    acc[i][1] = (f32x4){0.f, 0.f, 0.f, 0.f};
  }

  for (int st = 0; st < 8; ++st) {
    int sA = chunk * 512 + st * 64 + 2 * sp;
    const unsigned short* kp = Up + ((size_t)b * L_DIM + sA) * 512 + h * 64 + g * 8;
    uint4 ka = *(const uint4*)kp;
    uint4 kb = *(const uint4*)(kp + 512);
    int vr = ((sA >> 9) << 12) + ((sA & 511) << 3) + b;
    const unsigned short* vp = Vpb + (size_t)vr * 512 + h * 64 + g * 8;
    uint4 v0 = *(const uint4*)vp;
    uint4 v1 = *(const uint4*)(vp + 8 * 512);
    unsigned short ua[8], ub[8];
    *(uint4*)ua = ka;
    *(uint4*)ub = kb;
    float vA[8], vB[8];
    unpk8(v0, vA);
    unpk8(v1, vB);
    float sS = sintab[sA], sC = costab[sA];
    float tS = sintab[sA + 1], tC = costab[sA + 1];
    __syncthreads();  // previous iteration's MFMA LDS reads done
#pragma unroll
    for (int i = 0; i < 8; ++i) {
      int d = g * 8 + i;
      *(unsigned int*)&kT[swz64(d, 2 * sp)] =
          (unsigned int)ua[i] | ((unsigned int)ub[i] << 16);
    }
#pragma unroll
    for (int i = 0; i < 8; ++i) {
      int m = g * 8 + i;
      *(unsigned int*)&vT[swz64(m, 2 * sp)] = pkbf(vA[i] * sS, vB[i] * tS);
      *(unsigned int*)&vT[swz64(64 + m, 2 * sp)] = pkbf(vA[i] * sC, vB[i] * tC);
    }
    __syncthreads();
#pragma unroll
    for (int kk = 0; kk < 2; ++kk) {
      int ke = kk * 32 + lk;
      bf16x8 av[4], bv[2];
#pragma unroll
      for (int fm = 0; fm < 4; ++fm)
        av[fm] = *(const bf16x8*)&kT[swz64(fm * 16 + lr, ke)];
#pragma unroll
      for (int fn = 0; fn < 2; ++fn)
        bv[fn] = *(const bf16x8*)&vT[swz64(w * 32 + fn * 16 + lr, ke)];
#pragma unroll
      for (int fm = 0; fm < 4; ++fm)
#pragma unroll
        for (int fn = 0; fn < 2; ++fn)
          acc[fm][fn] = __builtin_amdgcn_mfma_f32_16x16x32_bf16(av[fm], bv[fn],
                                                                acc[fm][fn], 0, 0, 0);
    }
  }
  const int rq = lane >> 4;
#pragma unroll
  for (int fn = 0; fn < 2; ++fn) {
    int ncol = w * 32 + fn * 16 + lr;
    int m = ncol & 63;
    int ddbase = (ncol >> 6) * 64;
#pragma unroll
    for (int fm = 0; fm < 4; ++fm) {
#pragma unroll
      for (int jj = 0; jj < 4; ++jj) {
        int dd = ddbase + fm * 16 + rq * 4 + jj;
        kvpart[(((size_t)chunk * 64 + n) * 64 + m) * 128 + dd] = acc[fm][fn][jj];
      }
    }
  }
}

// reduce 8 chunks, normalize by 1/S, emit pre-swizzled bf16 kvT[n][m][dd']
__global__ void kv_reduce_swz(const float* __restrict__ part,
                              const float* __restrict__ colinv,
                              unsigned short* __restrict__ kvT) {
  int i = blockIdx.x * 256 + threadIdx.x;  // (n*64+m)*128+dd
  float s = 0.f;
#pragma unroll
  for (int c = 0; c < 8; ++c) s += part[(size_t)c * 524288 + i];
  int dd = i & 127;
  int m = (i >> 7) & 63;
  int n = i >> 13;
  float sc = colinv[(n >> 3) * 512 + (n & 7) * 64 + (dd & 63)];
  int gg = dd >> 3;
  int e = ((gg & 8) | ((gg ^ m) & 7)) * 8 + (dd & 7);
  kvT[(size_t)(i >> 7) * 128 + e] = f2bf(s * sc);
}

// ---------------------------------------------------------------------------
// Fused out pass, both terms (R8 known-good: vectorized Q loads, softmax via
// 8-lane-group shfl reduce, 1/sum folded into sin/cos scale).
// ---------------------------------------------------------------------------
__global__ __launch_bounds__(256) void out_fused(
    const unsigned short* __restrict__ Qp0, const unsigned short* __restrict__ Qp1,
    const unsigned short* __restrict__ kvT,
    const float* __restrict__ sintab, const float* __restrict__ costab,
    unsigned short* __restrict__ Yb) {
  __shared__ __align__(16) unsigned short q2s[64 * 128];
  __shared__ __align__(16) unsigned short kvs[2][64 * 128];
  const int tid = threadIdx.x;
  const int lc = blockIdx.x;
  const int n = blockIdx.y;
  const int b = n >> 3, h = n & 7;
  const int lane = tid & 63;
  const int w = tid >> 6;
  {
    const uint4* s0 = (const uint4*)(kvT + (size_t)n * 8192);
    const uint4* s1 = (const uint4*)(kvT + 524288 + (size_t)n * 8192);
    uint4* d0 = (uint4*)kvs[0];
    uint4* d1 = (uint4*)kvs[1];
#pragma unroll
    for (int i = 0; i < 4; ++i) {
      d0[tid + i * 256] = s0[tid + i * 256];
      d1[tid + i * 256] = s1[tid + i * 256];
    }
  }
  const int l0 = lc * 64;
  const int wr = w >> 1, wc = w & 1;
  const int lr = lane & 15;
  const int lk = (lane >> 4) * 8;
  const int rq = lane >> 4;
  f32x4 acc[2][2];
  acc[0][0] = acc[0][1] = acc[1][0] = acc[1][1] = (f32x4){0.f, 0.f, 0.f, 0.f};
#pragma unroll
  for (int t = 0; t < 2; ++t) {
    const unsigned short* Qp = t ? Qp1 : Qp0;
    if (t) __syncthreads();
#pragma unroll
    for (int i = 0; i < 2; ++i) {
      int idx = tid + i * 256;      // 0..511
      int row = idx >> 3;           // 0..63
      int g = idx & 7;
      uint4 q = *(const uint4*)(Qp + ((size_t)b * L_DIM + l0 + row) * 512 +
                                h * 64 + g * 8);
      float v[8];
      unpk8(q, v);
      float m8 = fmaxf(fmaxf(fmaxf(v[0], v[1]), fmaxf(v[2], v[3])),
                       fmaxf(fmaxf(v[4], v[5]), fmaxf(v[6], v[7])));
      m8 = fmaxf(m8, __shfl_xor(m8, 1));
      m8 = fmaxf(m8, __shfl_xor(m8, 2));
      m8 = fmaxf(m8, __shfl_xor(m8, 4));
      float e[8], s8;
#pragma unroll
      for (int k = 0; k < 8; ++k) e[k] = __expf(v[k] - m8);
      s8 = ((e[0] + e[1]) + (e[2] + e[3])) + ((e[4] + e[5]) + (e[6] + e[7]));
      s8 += __shfl_xor(s8, 1);
      s8 += __shfl_xor(s8, 2);
      s8 += __shfl_xor(s8, 4);
      float inv = 1.f / s8;
      int gl = l0 + row;
      float sn = sintab[gl] * inv;
      float cs = costab[gl] * inv;
      uint4 os, oc;
      os.x = pkbf(e[0] * sn, e[1] * sn); os.y = pkbf(e[2] * sn, e[3] * sn);
      os.z = pkbf(e[4] * sn, e[5] * sn); os.w = pkbf(e[6] * sn, e[7] * sn);
      oc.x = pkbf(e[0] * cs, e[1] * cs); oc.y = pkbf(e[2] * cs, e[3] * cs);
      oc.z = pkbf(e[4] * cs, e[5] * cs); oc.w = pkbf(e[6] * cs, e[7] * cs);
      *(uint4*)&q2s[swz128(row, g * 8)] = os;
      *(uint4*)&q2s[swz128(row, 64 + g * 8)] = oc;
    }
    __syncthreads();
#pragma unroll
    for (int ks = 0; ks < 4; ++ks) {
      int ke = ks * 32 + lk;
      bf16x8 av[2], bv[2];
#pragma unroll
      for (int fm = 0; fm < 2; ++fm)
        av[fm] = *(const bf16x8*)&q2s[swz128(wr * 32 + fm * 16 + lr, ke)];
#pragma unroll
      for (int fn = 0; fn < 2; ++fn)
        bv[fn] = *(const bf16x8*)&kvs[t][swz128(wc * 32 + fn * 16 + lr, ke)];
#pragma unroll
      for (int fm = 0; fm < 2; ++fm)
#pragma unroll
        for (int fn = 0; fn < 2; ++fn)
          acc[fm][fn] = __builtin_amdgcn_mfma_f32_16x16x32_bf16(av[fm], bv[fn],
                                                                acc[fm][fn], 0, 0, 0);
    }
  }
  __syncthreads();
  unsigned short* Os = q2s;  // 64 x (stride 72)
#pragma unroll
  for (int fn = 0; fn < 2; ++fn) {
    int col = wc * 32 + fn * 16 + lr;
#pragma unroll
    for (int fm = 0; fm < 2; ++fm) {
      int lrow = wr * 32 + fm * 16 + rq * 4;
#pragma unroll
      for (int jj = 0; jj < 4; ++jj)
        Os[(lrow + jj) * 72 + col] = f2bf(acc[fm][fn][jj]);
    }
  }
  __syncthreads();
#pragma unroll
  for (int i = 0; i < 2; ++i) {
    int idx = tid + i * 256;
    int row = idx >> 3, g = idx & 7;
    *(uint4*)(Yb + ((size_t)b * L_DIM + l0 + row) * 512 + h * 64 + g * 8) =
        *(const uint4*)&Os[row * 72 + g * 8];
  }
}

// ---------------------------------------------------------------------------
extern "C" void kernel_launch(void* const* d_in, const int* in_sizes, int n_in,
                              void* d_out, int out_size, void* d_ws, size_t ws_size,
                              hipStream_t stream) {
  const float* query = (const float*)d_in[0];
  const float* key   = (const float*)d_in[1];
  const float* value = (const float*)d_in[2];
  const float* Wq    = (const float*)d_in[3];
  const float* bq    = (const float*)d_in[4];
  const float* Wk    = (const float*)d_in[5];
  const float* bk    = (const float*)d_in[6];
  const float* Wv    = (const float*)d_in[7];
  const float* bv    = (const float*)d_in[8];
  const float* Wout  = (const float*)d_in[9];
  const float* bout  = (const float*)d_in[10];
  float* out = (float*)d_out;
  float* ws = (float*)d_ws;

  // workspace (fp32 slot units)
  const size_t F_PROJ0 = 0;                       // 32768x512 bf16 (t0)
  const size_t F_PROJ1 = F_PROJ0 + 8388608;       // 32768x512 bf16 (t1)
  const size_t F_VPB   = F_PROJ1 + 8388608;       // V proj bf16
  const size_t F_KVP   = F_VPB + 8388608;         // kv partials fp32 (aliases psum)
  const size_t F_KVT   = F_KVP + 4194304;         // kvT bf16, 2 terms
  const size_t F_XBUF  = F_KVT + 524288;          // attn-out bf16
  const size_t F_WBF   = F_XBUF + 8388608;        // weights bf16
  const size_t F_CINV  = F_WBF + 786432;          // 1/S, 2 terms x 4096
  const size_t F_SIN   = F_CINV + 8192;
  const size_t F_COS   = F_SIN + 4096;
  const size_t TOTALF  = F_COS + 4096;
  if (ws_size < TOTALF * sizeof(float)) {
    fprintf(stderr, "kernel_launch: ws too small (%zu < %zu)\n", ws_size, TOTALF * 4);
    return;
  }
  unsigned short* proj0 = (unsigned short*)(ws + F_PROJ0);
  unsigned short* vpb   = (unsigned short*)(ws + F_VPB);
  float* kvpart = ws + F_KVP;
  unsigned short* kvT  = (unsigned short*)(ws + F_KVT);
  unsigned short* xbuf = (unsigned short*)(ws + F_XBUF);
  unsigned short* wbf  = (unsigned short*)(ws + F_WBF);
  float* cinv = ws + F_CINV;
  float* sintab = ws + F_SIN;
  float* costab = ws + F_COS;
  // psum aliases kvpart (1 MB of 16 MB region): consumed by both colsum_reduce
  // launches BEFORE any kv_mfma writes kvpart.
  float* psum = kvpart;
  const size_t WQ_O = 0, WK_O = 524288, WV_O = 1048576, WOUT_O = 1310720;

  sincos_kernel<<<16, 256, 0, stream>>>(sintab, costab);
  convf2b<<<256, 256, 0, stream>>>(Wq, wbf + WQ_O, 65536);
  convf2b<<<256, 256, 0, stream>>>(Wk, wbf + WK_O, 65536);
  convf2b<<<128, 256, 0, stream>>>(Wv, wbf + WV_O, 32768);
  convf2b<<<128, 256, 0, stream>>>(Wout, wbf + WOUT_O, 32768);

  // V projection: value (fp32 A, converted in staging) -> vpb bf16
  gemm_xwt<true, 0, 2><<<1024, 256, 0, stream>>>(value, wbf + WV_O, bv, vpb,
                                                 nullptr);

  // K projections (both terms, N=1024): u = exp(logit) + fused column sums
  gemm_xwt<true, 2, 3><<<2048, 256, 0, stream>>>(key, wbf + WK_O, bk, proj0, psum);
  colsum_reduce<<<16, 256, 0, stream>>>(psum, cinv, 0);
  colsum_reduce<<<16, 256, 0, stream>>>(psum, cinv + 4096, 512);
  for (int t = 0; t < T_DIM; ++t) {
    unsigned short* projt = proj0 + (size_t)t * YHALF;
    kv_mfma<<<dim3(8, 64), 256, 0, stream>>>(projt, vpb, sintab, costab, kvpart);
    kv_reduce_swz<<<2048, 256, 0, stream>>>(kvpart, cinv + t * 4096,
                                            kvT + (size_t)t * 524288);
  }

  // Q projections (both terms, N=1024): fp32 A, plain bf16 store
  gemm_xwt<true, 0, 3><<<2048, 256, 0, stream>>>(query, wbf + WQ_O, bq, proj0,
                                                 nullptr);
  // fused output accumulation (q-softmax inside) -> xbuf
  out_fused<<<dim3(64, 64), 256, 0, stream>>>(proj0, proj0 + YHALF, kvT,
                                              sintab, costab, xbuf);
  // final projection: bf16 A (xbuf), fp32 out
  gemm_xwt<false, 1, 2><<<1024, 256, 0, stream>>>(xbuf, wbf + WOUT_O, bout, out,
                                                  nullptr);
}

// Round 13
// 319.385 us; speedup vs baseline: 1.3375x; 1.3375x over previous
//
#include <hip/hip_runtime.h>
#include <cstdio>

#define E_DIM 512
#define L_DIM 4096
#define B_DIM 8
#define H_DIM 8
#define T_DIM 2
#define M_ROWS 32768

typedef __attribute__((ext_vector_type(8))) __bf16 bf16x8;
typedef __attribute__((ext_vector_type(4))) float f32x4;

static __device__ __forceinline__ unsigned short f2bf(float f) {
  unsigned int u = __float_as_uint(f);
  return (unsigned short)((u + 0x7FFFu + ((u >> 16) & 1u)) >> 16);
}
static __device__ __forceinline__ unsigned int pkbf(float lo, float hi) {
  return (unsigned int)f2bf(lo) | ((unsigned int)f2bf(hi) << 16);
}
static __device__ __forceinline__ float bf2f(unsigned short u) {
  return __uint_as_float((unsigned int)u << 16);
}
static __device__ __forceinline__ void unpk8(uint4 u, float* f) {
  f[0] = bf2f((unsigned short)u.x); f[1] = bf2f((unsigned short)(u.x >> 16));
  f[2] = bf2f((unsigned short)u.y); f[3] = bf2f((unsigned short)(u.y >> 16));
  f[4] = bf2f((unsigned short)u.z); f[5] = bf2f((unsigned short)(u.z >> 16));
  f[6] = bf2f((unsigned short)u.w); f[7] = bf2f((unsigned short)(u.w >> 16));
}
// XOR swizzle at 8-elem (16B) granules
static __device__ __forceinline__ int swz64(int row, int e) {
  return row * 64 + ((((e >> 3) ^ row) & 7) << 3) + (e & 7);
}
static __device__ __forceinline__ int swz128(int row, int e) {
  return row * 128 + ((((e >> 3) ^ row) & 7) << 3) + ((e >> 3) & 8) * 8 + (e & 7);
}
// async global->LDS, 16B per lane; LDS dest = wave-uniform base + lane*16
static __device__ __forceinline__ void gl_lds16(const unsigned short* g,
                                                unsigned short* l) {
  __builtin_amdgcn_global_load_lds(
      (const __attribute__((address_space(1))) unsigned int*)g,
      (__attribute__((address_space(3))) unsigned int*)l, 16, 0, 0);
}

// ---------------------------------------------------------------------------
__global__ void sincos_kernel(float* __restrict__ sintab, float* __restrict__ costab) {
  int i = blockIdx.x * blockDim.x + threadIdx.x;
  if (i < L_DIM) {
    float idx = 1.57079632679489662f * (float)(i + 1) / (float)L_DIM;
    sintab[i] = sinf(idx);
    costab[i] = cosf(idx);
  }
}

__global__ void convf2b(const float* __restrict__ src, unsigned short* __restrict__ dst,
                        int n8) {
  for (int i = blockIdx.x * blockDim.x + threadIdx.x; i < n8; i += gridDim.x * blockDim.x) {
    float4 a = *(const float4*)(src + (size_t)i * 8);
    float4 b = *(const float4*)(src + (size_t)i * 8 + 4);
    uint4 o;
    o.x = pkbf(a.x, a.y); o.y = pkbf(a.z, a.w);
    o.z = pkbf(b.x, b.y); o.w = pkbf(b.z, b.w);
    *(uint4*)(dst + (size_t)i * 8) = o;
  }
}

// ---------------------------------------------------------------------------
// Y[M][N] = X[M][512] @ W[N][512]^T + bias[N]; N = 512<<(NBL2-2).
// MODE 0: plain bf16 store (split buffers at n=512, u16 stride YHALF)
// MODE 1: fp32 store
// MODE 2: u = exp(acc+bias) bf16 store + per-mtile column SUMS -> psum (K path)
// Main loop: double-buffered global_load_lds (linear dest, inverse-swz source).
// __launch_bounds__(256,2): LDS caps at 2 blocks/CU; let regalloc use VGPRs
// (R10 lesson: default bound gave 88 VGPR -> main-loop spill; R12 lesson:
// reg-staged fp32 A both spills and breaks coalescing — keep bf16-only A).
// ---------------------------------------------------------------------------
#define YHALF 16777216
template <int MODE, int NBL2>
__global__ __launch_bounds__(256, 2) void gemm_xwt(
    const unsigned short* __restrict__ X, const unsigned short* __restrict__ W,
    const float* __restrict__ bias, void* __restrict__ Yv,
    float* __restrict__ psum) {
  __shared__ __align__(16) unsigned short smem[32768];  // 2 x (As 8192 + Bs 8192)
  __shared__ float sf2[256];
  const int tid = threadIdx.x;
  const int id = blockIdx.x;
  const int j = id >> 3;
  const int mb = (id & 7) * 32 + (j >> NBL2);
  const int nb = j & ((1 << NBL2) - 1);
  const int m0 = mb * 128, n0 = nb * 128;
  const int lane = tid & 63;
  const int w = tid >> 6;
  const int wr = w >> 1, wc = w & 1;
  const int lr = lane & 15;
  const int lk = (lane >> 4) * 8;
  const int rq = lane >> 4;
  const int srow = lane >> 3;                 // 0..7
  const int gsrc8 = ((lane & 7) ^ srow) * 8;  // inverse-swizzled source granule
  f32x4 acc[4][4];
#pragma unroll
  for (int i = 0; i < 4; ++i)
#pragma unroll
    for (int jj = 0; jj < 4; ++jj) acc[i][jj] = (f32x4){0.f, 0.f, 0.f, 0.f};

  // prologue: stage tile 0 into buffer 0
#pragma unroll
  for (int i = 0; i < 4; ++i) {
    int rb = w * 32 + i * 8;
    gl_lds16(X + (size_t)(m0 + rb + srow) * 512 + gsrc8, &smem[rb * 64]);
    gl_lds16(W + (size_t)(n0 + rb + srow) * 512 + gsrc8, &smem[8192 + rb * 64]);
  }
  __syncthreads();

#pragma unroll
  for (int step = 0; step < 8; ++step) {
    const int cur = step & 1;
    if (step < 7) {
      unsigned short* Ab = smem + (cur ^ 1) * 16384;
      const int kn = (step + 1) * 64;
#pragma unroll
      for (int i = 0; i < 4; ++i) {
        int rb = w * 32 + i * 8;
        gl_lds16(X + (size_t)(m0 + rb + srow) * 512 + kn + gsrc8, &Ab[rb * 64]);
        gl_lds16(W + (size_t)(n0 + rb + srow) * 512 + kn + gsrc8,
                 &Ab[8192 + rb * 64]);
      }
    }
    const unsigned short* As = smem + cur * 16384;
    const unsigned short* Bs = As + 8192;
#pragma unroll
    for (int kk = 0; kk < 2; ++kk) {
      bf16x8 av[4], bv[4];
      int ke = kk * 32 + lk;
#pragma unroll
      for (int fm = 0; fm < 4; ++fm)
        av[fm] = *(const bf16x8*)&As[swz64(wr * 64 + fm * 16 + lr, ke)];
#pragma unroll
      for (int fn = 0; fn < 4; ++fn)
        bv[fn] = *(const bf16x8*)&Bs[swz64(wc * 64 + fn * 16 + lr, ke)];
#pragma unroll
      for (int fm = 0; fm < 4; ++fm)
#pragma unroll
        for (int fn = 0; fn < 4; ++fn)
          acc[fm][fn] = __builtin_amdgcn_mfma_f32_16x16x32_bf16(av[fm], bv[fn],
                                                                acc[fm][fn], 0, 0, 0);
    }
    __syncthreads();
  }

  // ---- epilogues ----
  if (MODE == 0 || MODE == 2) {
    unsigned short* Cs = smem;  // 128 x (stride 136) bf16 tile
    if (MODE == 0) {
#pragma unroll
      for (int fn = 0; fn < 4; ++fn) {
        int col = wc * 64 + fn * 16 + lr;
        float bb = bias[n0 + col];
#pragma unroll
        for (int fm = 0; fm < 4; ++fm) {
          int row = wr * 64 + fm * 16 + rq * 4;
#pragma unroll
          for (int jj = 0; jj < 4; ++jj)
            Cs[(row + jj) * 136 + col] = f2bf(acc[fm][fn][jj] + bb);
        }
      }
    } else {
      // MODE 2: u = exp(logit); per-column sums over this tile's 128 rows
#pragma unroll
      for (int fn = 0; fn < 4; ++fn) {
        int col = wc * 64 + fn * 16 + lr;
        float bb = bias[n0 + col];
        float S = 0.f;
#pragma unroll
        for (int fm = 0; fm < 4; ++fm) {
          int row = wr * 64 + fm * 16 + rq * 4;
#pragma unroll
          for (int jj = 0; jj < 4; ++jj) {
            float u = __expf(acc[fm][fn][jj] + bb);
            S += u;
            Cs[(row + jj) * 136 + col] = f2bf(u);
          }
        }
        S += __shfl_xor(S, 16);
        S += __shfl_xor(S, 32);
        if (rq == 0) sf2[wr * 128 + col] = S;
      }
    }
    __syncthreads();
    if (MODE == 2 && tid < 128) {
      float S = sf2[tid] + sf2[128 + tid];
      psum[(size_t)(m0 >> 7) * (128 << NBL2) + n0 + tid] = S;
    }
    unsigned short* Yb = (unsigned short*)Yv + (size_t)(n0 >> 9) * YHALF;
    const int nc = n0 & 511;
#pragma unroll
    for (int i = 0; i < 8; ++i) {
      int idx = tid + i * 256;     // 0..2047
      int row = idx >> 4, g = idx & 15;
      *(uint4*)(Yb + (size_t)(m0 + row) * 512 + nc + g * 8) =
          *(const uint4*)&Cs[row * 136 + g * 8];
    }
  } else {  // MODE 1: fp32 store
    float* Cf = (float*)smem;  // 64 x (stride 132)
    float* Yf = (float*)Yv;
#pragma unroll
    for (int p = 0; p < 2; ++p) {
      if (p) __syncthreads();
      if (wr == p) {
#pragma unroll
        for (int fn = 0; fn < 4; ++fn) {
          int col = wc * 64 + fn * 16 + lr;
          float bb = bias[n0 + col];
#pragma unroll
          for (int fm = 0; fm < 4; ++fm) {
            int lrow = fm * 16 + rq * 4;
#pragma unroll
            for (int jj = 0; jj < 4; ++jj)
              Cf[(lrow + jj) * 132 + col] = acc[fm][fn][jj] + bb;
          }
        }
      }
      __syncthreads();
#pragma unroll
      for (int i = 0; i < 8; ++i) {
        int idx = tid + i * 256;
        int row = idx >> 5, g = idx & 31;
        *(float4*)(Yf + (size_t)(m0 + p * 64 + row) * 512 + n0 + g * 4) =
            *(const float4*)&Cf[row * 132 + g * 4];
      }
    }
  }
}

// ---------------------------------------------------------------------------
// column-sum reduce over the 32 mtiles of each b -> 1/S ; both terms in one
// launch (grid 32: block>>4 selects term)
// ---------------------------------------------------------------------------
__global__ void colsum_reduce2(const float* __restrict__ psum,
                               float* __restrict__ colinv) {
  int t = blockIdx.x >> 4;
  int i = (blockIdx.x & 15) * 256 + threadIdx.x;  // b*512+f, 0..4095
  int b = i >> 9, f = i & 511;
  float S = 0.f;
#pragma unroll
  for (int c = 0; c < 32; ++c)
    S += psum[(size_t)(b * 32 + c) * 1024 + t * 512 + f];
  colinv[t * 4096 + i] = 1.f / S;
}

// ---------------------------------------------------------------------------
// kv partials via MFMA: C[d][ncol] = sum_s u[s][d]*B[s][ncol], B=[v*sin|v*cos]
// u is pre-exp'd bf16 (no front-end math). grid (8 s-chunks, 64 n), 256 thr.
// ---------------------------------------------------------------------------
__global__ __launch_bounds__(256) void kv_mfma(
    const unsigned short* __restrict__ Up, const unsigned short* __restrict__ Vpb,
    const float* __restrict__ sintab, const float* __restrict__ costab,
    float* __restrict__ kvpart) {
  __shared__ __align__(16) unsigned short kT[64 * 64];
  __shared__ __align__(16) unsigned short vT[128 * 64];
  const int tid = threadIdx.x;
  const int chunk = blockIdx.x;
  const int n = blockIdx.y;
  const int b = n >> 3, h = n & 7;
  const int lane = tid & 63;
  const int w = tid >> 6;
  const int lr = lane & 15;
  const int lk = (lane >> 4) * 8;
  const int sp = tid & 31;
  const int g = tid >> 5;
  f32x4 acc[4][2];
#pragma unroll
  for (int i = 0; i < 4; ++i) {
    acc[i][0] = (f32x4){0.f, 0.f, 0.f, 0.f};
    acc[i][1] = (f32x4){0.f, 0.f, 0.f, 0.f};
  }

  for (int st = 0; st < 8; ++st) {
    int sA = chunk * 512 + st * 64 + 2 * sp;
    const unsigned short* kp = Up + ((size_t)b * L_DIM + sA) * 512 + h * 64 + g * 8;
    uint4 ka = *(const uint4*)kp;
    uint4 kb = *(const uint4*)(kp + 512);
    int vr = ((sA >> 9) << 12) + ((sA & 511) << 3) + b;
    const unsigned short* vp = Vpb + (size_t)vr * 512 + h * 64 + g * 8;
    uint4 v0 = *(const uint4*)vp;
    uint4 v1 = *(const uint4*)(vp + 8 * 512);
    unsigned short ua[8], ub[8];
    *(uint4*)ua = ka;
    *(uint4*)ub = kb;
    float vA[8], vB[8];
    unpk8(v0, vA);
    unpk8(v1, vB);
    float sS = sintab[sA], sC = costab[sA];
    float tS = sintab[sA + 1], tC = costab[sA + 1];
    __syncthreads();  // previous iteration's MFMA LDS reads done
#pragma unroll
    for (int i = 0; i < 8; ++i) {
      int d = g * 8 + i;
      *(unsigned int*)&kT[swz64(d, 2 * sp)] =
          (unsigned int)ua[i] | ((unsigned int)ub[i] << 16);
    }
#pragma unroll
    for (int i = 0; i < 8; ++i) {
      int m = g * 8 + i;
      *(unsigned int*)&vT[swz64(m, 2 * sp)] = pkbf(vA[i] * sS, vB[i] * tS);
      *(unsigned int*)&vT[swz64(64 + m, 2 * sp)] = pkbf(vA[i] * sC, vB[i] * tC);
    }
    __syncthreads();
#pragma unroll
    for (int kk = 0; kk < 2; ++kk) {
      int ke = kk * 32 + lk;
      bf16x8 av[4], bv[2];
#pragma unroll
      for (int fm = 0; fm < 4; ++fm)
        av[fm] = *(const bf16x8*)&kT[swz64(fm * 16 + lr, ke)];
#pragma unroll
      for (int fn = 0; fn < 2; ++fn)
        bv[fn] = *(const bf16x8*)&vT[swz64(w * 32 + fn * 16 + lr, ke)];
#pragma unroll
      for (int fm = 0; fm < 4; ++fm)
#pragma unroll
        for (int fn = 0; fn < 2; ++fn)
          acc[fm][fn] = __builtin_amdgcn_mfma_f32_16x16x32_bf16(av[fm], bv[fn],
                                                                acc[fm][fn], 0, 0, 0);
    }
  }
  const int rq = lane >> 4;
#pragma unroll
  for (int fn = 0; fn < 2; ++fn) {
    int ncol = w * 32 + fn * 16 + lr;
    int m = ncol & 63;
    int ddbase = (ncol >> 6) * 64;
#pragma unroll
    for (int fm = 0; fm < 4; ++fm) {
#pragma unroll
      for (int jj = 0; jj < 4; ++jj) {
        int dd = ddbase + fm * 16 + rq * 4 + jj;
        kvpart[(((size_t)chunk * 64 + n) * 64 + m) * 128 + dd] = acc[fm][fn][jj];
      }
    }
  }
}

// reduce 8 chunks, normalize by 1/S, emit pre-swizzled bf16 kvT[n][m][dd']
__global__ void kv_reduce_swz(const float* __restrict__ part,
                              const float* __restrict__ colinv,
                              unsigned short* __restrict__ kvT) {
  int i = blockIdx.x * 256 + threadIdx.x;  // (n*64+m)*128+dd
  float s = 0.f;
#pragma unroll
  for (int c = 0; c < 8; ++c) s += part[(size_t)c * 524288 + i];
  int dd = i & 127;
  int m = (i >> 7) & 63;
  int n = i >> 13;
  float sc = colinv[(n >> 3) * 512 + (n & 7) * 64 + (dd & 63)];
  int gg = dd >> 3;
  int e = ((gg & 8) | ((gg ^ m) & 7)) * 8 + (dd & 7);
  kvT[(size_t)(i >> 7) * 128 + e] = f2bf(s * sc);
}

// ---------------------------------------------------------------------------
// Fused out pass, both terms (R8 known-good: vectorized Q loads, softmax via
// 8-lane-group shfl reduce, 1/sum folded into sin/cos scale).
// ---------------------------------------------------------------------------
__global__ __launch_bounds__(256) void out_fused(
    const unsigned short* __restrict__ Qp0, const unsigned short* __restrict__ Qp1,
    const unsigned short* __restrict__ kvT,
    const float* __restrict__ sintab, const float* __restrict__ costab,
    unsigned short* __restrict__ Yb) {
  __shared__ __align__(16) unsigned short q2s[64 * 128];
  __shared__ __align__(16) unsigned short kvs[2][64 * 128];
  const int tid = threadIdx.x;
  const int lc = blockIdx.x;
  const int n = blockIdx.y;
  const int b = n >> 3, h = n & 7;
  const int lane = tid & 63;
  const int w = tid >> 6;
  {
    const uint4* s0 = (const uint4*)(kvT + (size_t)n * 8192);
    const uint4* s1 = (const uint4*)(kvT + 524288 + (size_t)n * 8192);
    uint4* d0 = (uint4*)kvs[0];
    uint4* d1 = (uint4*)kvs[1];
#pragma unroll
    for (int i = 0; i < 4; ++i) {
      d0[tid + i * 256] = s0[tid + i * 256];
      d1[tid + i * 256] = s1[tid + i * 256];
    }
  }
  const int l0 = lc * 64;
  const int wr = w >> 1, wc = w & 1;
  const int lr = lane & 15;
  const int lk = (lane >> 4) * 8;
  const int rq = lane >> 4;
  f32x4 acc[2][2];
  acc[0][0] = acc[0][1] = acc[1][0] = acc[1][1] = (f32x4){0.f, 0.f, 0.f, 0.f};
#pragma unroll
  for (int t = 0; t < 2; ++t) {
    const unsigned short* Qp = t ? Qp1 : Qp0;
    if (t) __syncthreads();
#pragma unroll
    for (int i = 0; i < 2; ++i) {
      int idx = tid + i * 256;      // 0..511
      int row = idx >> 3;           // 0..63
      int g = idx & 7;
      uint4 q = *(const uint4*)(Qp + ((size_t)b * L_DIM + l0 + row) * 512 +
                                h * 64 + g * 8);
      float v[8];
      unpk8(q, v);
      float m8 = fmaxf(fmaxf(fmaxf(v[0], v[1]), fmaxf(v[2], v[3])),
                       fmaxf(fmaxf(v[4], v[5]), fmaxf(v[6], v[7])));
      m8 = fmaxf(m8, __shfl_xor(m8, 1));
      m8 = fmaxf(m8, __shfl_xor(m8, 2));
      m8 = fmaxf(m8, __shfl_xor(m8, 4));
      float e[8], s8;
#pragma unroll
      for (int k = 0; k < 8; ++k) e[k] = __expf(v[k] - m8);
      s8 = ((e[0] + e[1]) + (e[2] + e[3])) + ((e[4] + e[5]) + (e[6] + e[7]));
      s8 += __shfl_xor(s8, 1);
      s8 += __shfl_xor(s8, 2);
      s8 += __shfl_xor(s8, 4);
      float inv = 1.f / s8;
      int gl = l0 + row;
      float sn = sintab[gl] * inv;
      float cs = costab[gl] * inv;
      uint4 os, oc;
      os.x = pkbf(e[0] * sn, e[1] * sn); os.y = pkbf(e[2] * sn, e[3] * sn);
      os.z = pkbf(e[4] * sn, e[5] * sn); os.w = pkbf(e[6] * sn, e[7] * sn);
      oc.x = pkbf(e[0] * cs, e[1] * cs); oc.y = pkbf(e[2] * cs, e[3] * cs);
      oc.z = pkbf(e[4] * cs, e[5] * cs); oc.w = pkbf(e[6] * cs, e[7] * cs);
      *(uint4*)&q2s[swz128(row, g * 8)] = os;
      *(uint4*)&q2s[swz128(row, 64 + g * 8)] = oc;
    }
    __syncthreads();
#pragma unroll
    for (int ks = 0; ks < 4; ++ks) {
      int ke = ks * 32 + lk;
      bf16x8 av[2], bv[2];
#pragma unroll
      for (int fm = 0; fm < 2; ++fm)
        av[fm] = *(const bf16x8*)&q2s[swz128(wr * 32 + fm * 16 + lr, ke)];
#pragma unroll
      for (int fn = 0; fn < 2; ++fn)
        bv[fn] = *(const bf16x8*)&kvs[t][swz128(wc * 32 + fn * 16 + lr, ke)];
#pragma unroll
      for (int fm = 0; fm < 2; ++fm)
#pragma unroll
        for (int fn = 0; fn < 2; ++fn)
          acc[fm][fn] = __builtin_amdgcn_mfma_f32_16x16x32_bf16(av[fm], bv[fn],
                                                                acc[fm][fn], 0, 0, 0);
    }
  }
  __syncthreads();
  unsigned short* Os = q2s;  // 64 x (stride 72)
#pragma unroll
  for (int fn = 0; fn < 2; ++fn) {
    int col = wc * 32 + fn * 16 + lr;
#pragma unroll
    for (int fm = 0; fm < 2; ++fm) {
      int lrow = wr * 32 + fm * 16 + rq * 4;
#pragma unroll
      for (int jj = 0; jj < 4; ++jj)
        Os[(lrow + jj) * 72 + col] = f2bf(acc[fm][fn][jj]);
    }
  }
  __syncthreads();
#pragma unroll
  for (int i = 0; i < 2; ++i) {
    int idx = tid + i * 256;
    int row = idx >> 3, g = idx & 7;
    *(uint4*)(Yb + ((size_t)b * L_DIM + l0 + row) * 512 + h * 64 + g * 8) =
        *(const uint4*)&Os[row * 72 + g * 8];
  }
}

// ---------------------------------------------------------------------------
extern "C" void kernel_launch(void* const* d_in, const int* in_sizes, int n_in,
                              void* d_out, int out_size, void* d_ws, size_t ws_size,
                              hipStream_t stream) {
  const float* query = (const float*)d_in[0];
  const float* key   = (const float*)d_in[1];
  const float* value = (const float*)d_in[2];
  const float* Wq    = (const float*)d_in[3];
  const float* bq    = (const float*)d_in[4];
  const float* Wk    = (const float*)d_in[5];
  const float* bk    = (const float*)d_in[6];
  const float* Wv    = (const float*)d_in[7];
  const float* bv    = (const float*)d_in[8];
  const float* Wout  = (const float*)d_in[9];
  const float* bout  = (const float*)d_in[10];
  float* out = (float*)d_out;
  float* ws = (float*)d_ws;

  // workspace (fp32 slot units)
  const size_t F_PROJ0 = 0;                       // 32768x512 bf16 (t0)
  const size_t F_PROJ1 = F_PROJ0 + 8388608;       // 32768x512 bf16 (t1)
  const size_t F_VPB   = F_PROJ1 + 8388608;       // V proj bf16
  const size_t F_KVP   = F_VPB + 8388608;         // kv partials fp32 (aliases psum)
  const size_t F_KVT   = F_KVP + 4194304;         // kvT bf16, 2 terms
  const size_t F_XBUF  = F_KVT + 524288;          // bf16 input / attn-out (shared)
  const size_t F_WBF   = F_XBUF + 8388608;        // weights bf16
  const size_t F_CINV  = F_WBF + 786432;          // 1/S, 2 terms x 4096
  const size_t F_SIN   = F_CINV + 8192;
  const size_t F_COS   = F_SIN + 4096;
  const size_t TOTALF  = F_COS + 4096;
  if (ws_size < TOTALF * sizeof(float)) {
    fprintf(stderr, "kernel_launch: ws too small (%zu < %zu)\n", ws_size, TOTALF * 4);
    return;
  }
  unsigned short* proj0 = (unsigned short*)(ws + F_PROJ0);
  unsigned short* vpb   = (unsigned short*)(ws + F_VPB);
  float* kvpart = ws + F_KVP;
  unsigned short* kvT  = (unsigned short*)(ws + F_KVT);
  unsigned short* xbuf = (unsigned short*)(ws + F_XBUF);
  unsigned short* wbf  = (unsigned short*)(ws + F_WBF);
  float* cinv = ws + F_CINV;
  float* sintab = ws + F_SIN;
  float* costab = ws + F_COS;
  // psum aliases kvpart (1 MB of 16 MB region): consumed by colsum_reduce2
  // BEFORE any kv_mfma writes kvpart.
  float* psum = kvpart;
  const size_t WQ_O = 0, WK_O = 524288, WV_O = 1048576, WOUT_O = 1310720;

  sincos_kernel<<<16, 256, 0, stream>>>(sintab, costab);
  convf2b<<<256, 256, 0, stream>>>(Wq, wbf + WQ_O, 65536);
  convf2b<<<256, 256, 0, stream>>>(Wk, wbf + WK_O, 65536);
  convf2b<<<128, 256, 0, stream>>>(Wv, wbf + WV_O, 32768);
  convf2b<<<128, 256, 0, stream>>>(Wout, wbf + WOUT_O, 32768);

  // V projection: value -> bf16 (xbuf) -> GEMM -> vpb
  convf2b<<<2048, 256, 0, stream>>>(value, xbuf, 2097152);
  gemm_xwt<0, 2><<<1024, 256, 0, stream>>>(xbuf, wbf + WV_O, bv, vpb, nullptr);

  // K projections (both terms, N=1024): u = exp(logit) + fused column sums
  convf2b<<<2048, 256, 0, stream>>>(key, xbuf, 2097152);
  gemm_xwt<2, 3><<<2048, 256, 0, stream>>>(xbuf, wbf + WK_O, bk, proj0, psum);
  colsum_reduce2<<<32, 256, 0, stream>>>(psum, cinv);
  for (int t = 0; t < T_DIM; ++t) {
    unsigned short* projt = proj0 + (size_t)t * YHALF;
    kv_mfma<<<dim3(8, 64), 256, 0, stream>>>(projt, vpb, sintab, costab, kvpart);
    kv_reduce_swz<<<2048, 256, 0, stream>>>(kvpart, cinv + t * 4096,
                                            kvT + (size_t)t * 524288);
  }

  // Q projections (both terms, N=1024): plain bf16 store
  convf2b<<<2048, 256, 0, stream>>>(query, xbuf, 2097152);
  gemm_xwt<0, 3><<<2048, 256, 0, stream>>>(xbuf, wbf + WQ_O, bq, proj0, nullptr);
  // fused output accumulation (q-softmax inside) -> xbuf
  out_fused<<<dim3(64, 64), 256, 0, stream>>>(proj0, proj0 + YHALF, kvT,
                                              sintab, costab, xbuf);
  // final projection: bf16 A, fp32 out
  gemm_xwt<1, 2><<<1024, 256, 0, stream>>>(xbuf, wbf + WOUT_O, bout, out, nullptr);
}

// Round 14
// 316.047 us; speedup vs baseline: 1.3516x; 1.0106x over previous
//
#include <hip/hip_runtime.h>
#include <cstdio>

#define E_DIM 512
#define L_DIM 4096
#define B_DIM 8
#define H_DIM 8
#define T_DIM 2
#define M_ROWS 32768

typedef __attribute__((ext_vector_type(8))) __bf16 bf16x8;
typedef __attribute__((ext_vector_type(4))) float f32x4;

static __device__ __forceinline__ unsigned short f2bf(float f) {
  unsigned int u = __float_as_uint(f);
  return (unsigned short)((u + 0x7FFFu + ((u >> 16) & 1u)) >> 16);
}
static __device__ __forceinline__ unsigned int pkbf(float lo, float hi) {
  return (unsigned int)f2bf(lo) | ((unsigned int)f2bf(hi) << 16);
}
static __device__ __forceinline__ float bf2f(unsigned short u) {
  return __uint_as_float((unsigned int)u << 16);
}
static __device__ __forceinline__ void unpk8(uint4 u, float* f) {
  f[0] = bf2f((unsigned short)u.x); f[1] = bf2f((unsigned short)(u.x >> 16));
  f[2] = bf2f((unsigned short)u.y); f[3] = bf2f((unsigned short)(u.y >> 16));
  f[4] = bf2f((unsigned short)u.z); f[5] = bf2f((unsigned short)(u.z >> 16));
  f[6] = bf2f((unsigned short)u.w); f[7] = bf2f((unsigned short)(u.w >> 16));
}
// XOR swizzle at 8-elem (16B) granules
static __device__ __forceinline__ int swz64(int row, int e) {
  return row * 64 + ((((e >> 3) ^ row) & 7) << 3) + (e & 7);
}
static __device__ __forceinline__ int swz128(int row, int e) {
  return row * 128 + ((((e >> 3) ^ row) & 7) << 3) + ((e >> 3) & 8) * 8 + (e & 7);
}
// async global->LDS, 16B per lane; LDS dest = wave-uniform base + lane*16
static __device__ __forceinline__ void gl_lds16(const unsigned short* g,
                                                unsigned short* l) {
  __builtin_amdgcn_global_load_lds(
      (const __attribute__((address_space(1))) unsigned int*)g,
      (__attribute__((address_space(3))) unsigned int*)l, 16, 0, 0);
}

// ---------------------------------------------------------------------------
__global__ void sincos_kernel(float* __restrict__ sintab, float* __restrict__ costab) {
  int i = blockIdx.x * blockDim.x + threadIdx.x;
  if (i < L_DIM) {
    float idx = 1.57079632679489662f * (float)(i + 1) / (float)L_DIM;
    sintab[i] = sinf(idx);
    costab[i] = cosf(idx);
  }
}

__global__ void convf2b(const float* __restrict__ src, unsigned short* __restrict__ dst,
                        int n8) {
  for (int i = blockIdx.x * blockDim.x + threadIdx.x; i < n8; i += gridDim.x * blockDim.x) {
    float4 a = *(const float4*)(src + (size_t)i * 8);
    float4 b = *(const float4*)(src + (size_t)i * 8 + 4);
    uint4 o;
    o.x = pkbf(a.x, a.y); o.y = pkbf(a.z, a.w);
    o.z = pkbf(b.x, b.y); o.w = pkbf(b.z, b.w);
    *(uint4*)(dst + (size_t)i * 8) = o;
  }
}

// ---------------------------------------------------------------------------
// Y[M][N] = X[M][512] @ W[N][512]^T + bias[N]; N = 512<<(NBL2-2).
// MODE 0: plain bf16 store (split buffers at n=512, u16 stride YHALF)
// MODE 1: fp32 store
// MODE 2: u = exp(acc+bias) bf16 store + per-mtile column SUMS -> psum (K path)
// Main loop: double-buffered global_load_lds (linear dest, inverse-swz source).
// __launch_bounds__(256,2): LDS caps at 2 blocks/CU; let regalloc use VGPRs
// (R10 lesson: default bound gave 88 VGPR -> main-loop spill; R12 lesson:
// reg-staged fp32 A both spills and breaks coalescing — keep bf16-only A).
// ---------------------------------------------------------------------------
#define YHALF 16777216
template <int MODE, int NBL2>
__global__ __launch_bounds__(256, 2) void gemm_xwt(
    const unsigned short* __restrict__ X, const unsigned short* __restrict__ W,
    const float* __restrict__ bias, void* __restrict__ Yv,
    float* __restrict__ psum) {
  __shared__ __align__(16) unsigned short smem[32768];  // 2 x (As 8192 + Bs 8192)
  __shared__ float sf2[256];
  const int tid = threadIdx.x;
  const int id = blockIdx.x;
  const int j = id >> 3;
  const int mb = (id & 7) * 32 + (j >> NBL2);
  const int nb = j & ((1 << NBL2) - 1);
  const int m0 = mb * 128, n0 = nb * 128;
  const int lane = tid & 63;
  const int w = tid >> 6;
  const int wr = w >> 1, wc = w & 1;
  const int lr = lane & 15;
  const int lk = (lane >> 4) * 8;
  const int rq = lane >> 4;
  const int srow = lane >> 3;                 // 0..7
  const int gsrc8 = ((lane & 7) ^ srow) * 8;  // inverse-swizzled source granule
  f32x4 acc[4][4];
#pragma unroll
  for (int i = 0; i < 4; ++i)
#pragma unroll
    for (int jj = 0; jj < 4; ++jj) acc[i][jj] = (f32x4){0.f, 0.f, 0.f, 0.f};

  // prologue: stage tile 0 into buffer 0
#pragma unroll
  for (int i = 0; i < 4; ++i) {
    int rb = w * 32 + i * 8;
    gl_lds16(X + (size_t)(m0 + rb + srow) * 512 + gsrc8, &smem[rb * 64]);
    gl_lds16(W + (size_t)(n0 + rb + srow) * 512 + gsrc8, &smem[8192 + rb * 64]);
  }
  __syncthreads();

#pragma unroll
  for (int step = 0; step < 8; ++step) {
    const int cur = step & 1;
    if (step < 7) {
      unsigned short* Ab = smem + (cur ^ 1) * 16384;
      const int kn = (step + 1) * 64;
#pragma unroll
      for (int i = 0; i < 4; ++i) {
        int rb = w * 32 + i * 8;
        gl_lds16(X + (size_t)(m0 + rb + srow) * 512 + kn + gsrc8, &Ab[rb * 64]);
        gl_lds16(W + (size_t)(n0 + rb + srow) * 512 + kn + gsrc8,
                 &Ab[8192 + rb * 64]);
      }
    }
    const unsigned short* As = smem + cur * 16384;
    const unsigned short* Bs = As + 8192;
#pragma unroll
    for (int kk = 0; kk < 2; ++kk) {
      bf16x8 av[4], bv[4];
      int ke = kk * 32 + lk;
#pragma unroll
      for (int fm = 0; fm < 4; ++fm)
        av[fm] = *(const bf16x8*)&As[swz64(wr * 64 + fm * 16 + lr, ke)];
#pragma unroll
      for (int fn = 0; fn < 4; ++fn)
        bv[fn] = *(const bf16x8*)&Bs[swz64(wc * 64 + fn * 16 + lr, ke)];
#pragma unroll
      for (int fm = 0; fm < 4; ++fm)
#pragma unroll
        for (int fn = 0; fn < 4; ++fn)
          acc[fm][fn] = __builtin_amdgcn_mfma_f32_16x16x32_bf16(av[fm], bv[fn],
                                                                acc[fm][fn], 0, 0, 0);
    }
    __syncthreads();
  }

  // ---- epilogues ----
  if (MODE == 0 || MODE == 2) {
    unsigned short* Cs = smem;  // 128 x (stride 136) bf16 tile
    if (MODE == 0) {
#pragma unroll
      for (int fn = 0; fn < 4; ++fn) {
        int col = wc * 64 + fn * 16 + lr;
        float bb = bias[n0 + col];
#pragma unroll
        for (int fm = 0; fm < 4; ++fm) {
          int row = wr * 64 + fm * 16 + rq * 4;
#pragma unroll
          for (int jj = 0; jj < 4; ++jj)
            Cs[(row + jj) * 136 + col] = f2bf(acc[fm][fn][jj] + bb);
        }
      }
    } else {
      // MODE 2: u = exp(logit); per-column sums over this tile's 128 rows
#pragma unroll
      for (int fn = 0; fn < 4; ++fn) {
        int col = wc * 64 + fn * 16 + lr;
        float bb = bias[n0 + col];
        float S = 0.f;
#pragma unroll
        for (int fm = 0; fm < 4; ++fm) {
          int row = wr * 64 + fm * 16 + rq * 4;
#pragma unroll
          for (int jj = 0; jj < 4; ++jj) {
            float u = __expf(acc[fm][fn][jj] + bb);
            S += u;
            Cs[(row + jj) * 136 + col] = f2bf(u);
          }
        }
        S += __shfl_xor(S, 16);
        S += __shfl_xor(S, 32);
        if (rq == 0) sf2[wr * 128 + col] = S;
      }
    }
    __syncthreads();
    if (MODE == 2 && tid < 128) {
      float S = sf2[tid] + sf2[128 + tid];
      psum[(size_t)(m0 >> 7) * (128 << NBL2) + n0 + tid] = S;
    }
    unsigned short* Yb = (unsigned short*)Yv + (size_t)(n0 >> 9) * YHALF;
    const int nc = n0 & 511;
#pragma unroll
    for (int i = 0; i < 8; ++i) {
      int idx = tid + i * 256;     // 0..2047
      int row = idx >> 4, g = idx & 15;
      *(uint4*)(Yb + (size_t)(m0 + row) * 512 + nc + g * 8) =
          *(const uint4*)&Cs[row * 136 + g * 8];
    }
  } else {  // MODE 1: fp32 store
    float* Cf = (float*)smem;  // 64 x (stride 132)
    float* Yf = (float*)Yv;
#pragma unroll
    for (int p = 0; p < 2; ++p) {
      if (p) __syncthreads();
      if (wr == p) {
#pragma unroll
        for (int fn = 0; fn < 4; ++fn) {
          int col = wc * 64 + fn * 16 + lr;
          float bb = bias[n0 + col];
#pragma unroll
          for (int fm = 0; fm < 4; ++fm) {
            int lrow = fm * 16 + rq * 4;
#pragma unroll
            for (int jj = 0; jj < 4; ++jj)
              Cf[(lrow + jj) * 132 + col] = acc[fm][fn][jj] + bb;
          }
        }
      }
      __syncthreads();
#pragma unroll
      for (int i = 0; i < 8; ++i) {
        int idx = tid + i * 256;
        int row = idx >> 5, g = idx & 31;
        *(float4*)(Yf + (size_t)(m0 + p * 64 + row) * 512 + n0 + g * 4) =
            *(const float4*)&Cf[row * 132 + g * 4];
      }
    }
  }
}

// ---------------------------------------------------------------------------
// column-sum reduce over the 32 mtiles of each b -> 1/S ; both terms in one
// launch (grid 32: block>>4 selects term)
// ---------------------------------------------------------------------------
__global__ void colsum_reduce2(const float* __restrict__ psum,
                               float* __restrict__ colinv) {
  int t = blockIdx.x >> 4;
  int i = (blockIdx.x & 15) * 256 + threadIdx.x;  // b*512+f, 0..4095
  int b = i >> 9, f = i & 511;
  float S = 0.f;
#pragma unroll
  for (int c = 0; c < 32; ++c)
    S += psum[(size_t)(b * 32 + c) * 1024 + t * 512 + f];
  colinv[t * 4096 + i] = 1.f / S;
}

// ---------------------------------------------------------------------------
// kv partials via MFMA: C[d][ncol] = sum_s u[s][d]*B[s][ncol], B=[v*sin|v*cos]
// u is pre-exp'd bf16 (no front-end math). grid (8 s-chunks, 64 n), 256 thr.
// ---------------------------------------------------------------------------
__global__ __launch_bounds__(256) void kv_mfma(
    const unsigned short* __restrict__ Up, const unsigned short* __restrict__ Vpb,
    const float* __restrict__ sintab, const float* __restrict__ costab,
    float* __restrict__ kvpart) {
  __shared__ __align__(16) unsigned short kT[64 * 64];
  __shared__ __align__(16) unsigned short vT[128 * 64];
  const int tid = threadIdx.x;
  const int chunk = blockIdx.x;
  const int n = blockIdx.y;
  const int b = n >> 3, h = n & 7;
  const int lane = tid & 63;
  const int w = tid >> 6;
  const int lr = lane & 15;
  const int lk = (lane >> 4) * 8;
  const int sp = tid & 31;
  const int g = tid >> 5;
  f32x4 acc[4][2];
#pragma unroll
  for (int i = 0; i < 4; ++i) {
    acc[i][0] = (f32x4){0.f, 0.f, 0.f, 0.f};
    acc[i][1] = (f32x4){0.f, 0.f, 0.f, 0.f};
  }

  for (int st = 0; st < 8; ++st) {
    int sA = chunk * 512 + st * 64 + 2 * sp;
    const unsigned short* kp = Up + ((size_t)b * L_DIM + sA) * 512 + h * 64 + g * 8;
    uint4 ka = *(const uint4*)kp;
    uint4 kb = *(const uint4*)(kp + 512);
    int vr = ((sA >> 9) << 12) + ((sA & 511) << 3) + b;
    const unsigned short* vp = Vpb + (size_t)vr * 512 + h * 64 + g * 8;
    uint4 v0 = *(const uint4*)vp;
    uint4 v1 = *(const uint4*)(vp + 8 * 512);
    unsigned short ua[8], ub[8];
    *(uint4*)ua = ka;
    *(uint4*)ub = kb;
    float vA[8], vB[8];
    unpk8(v0, vA);
    unpk8(v1, vB);
    float sS = sintab[sA], sC = costab[sA];
    float tS = sintab[sA + 1], tC = costab[sA + 1];
    __syncthreads();  // previous iteration's MFMA LDS reads done
#pragma unroll
    for (int i = 0; i < 8; ++i) {
      int d = g * 8 + i;
      *(unsigned int*)&kT[swz64(d, 2 * sp)] =
          (unsigned int)ua[i] | ((unsigned int)ub[i] << 16);
    }
#pragma unroll
    for (int i = 0; i < 8; ++i) {
      int m = g * 8 + i;
      *(unsigned int*)&vT[swz64(m, 2 * sp)] = pkbf(vA[i] * sS, vB[i] * tS);
      *(unsigned int*)&vT[swz64(64 + m, 2 * sp)] = pkbf(vA[i] * sC, vB[i] * tC);
    }
    __syncthreads();
#pragma unroll
    for (int kk = 0; kk < 2; ++kk) {
      int ke = kk * 32 + lk;
      bf16x8 av[4], bv[2];
#pragma unroll
      for (int fm = 0; fm < 4; ++fm)
        av[fm] = *(const bf16x8*)&kT[swz64(fm * 16 + lr, ke)];
#pragma unroll
      for (int fn = 0; fn < 2; ++fn)
        bv[fn] = *(const bf16x8*)&vT[swz64(w * 32 + fn * 16 + lr, ke)];
#pragma unroll
      for (int fm = 0; fm < 4; ++fm)
#pragma unroll
        for (int fn = 0; fn < 2; ++fn)
          acc[fm][fn] = __builtin_amdgcn_mfma_f32_16x16x32_bf16(av[fm], bv[fn],
                                                                acc[fm][fn], 0, 0, 0);
    }
  }
  const int rq = lane >> 4;
#pragma unroll
  for (int fn = 0; fn < 2; ++fn) {
    int ncol = w * 32 + fn * 16 + lr;
    int m = ncol & 63;
    int ddbase = (ncol >> 6) * 64;
#pragma unroll
    for (int fm = 0; fm < 4; ++fm) {
#pragma unroll
      for (int jj = 0; jj < 4; ++jj) {
        int dd = ddbase + fm * 16 + rq * 4 + jj;
        kvpart[(((size_t)chunk * 64 + n) * 64 + m) * 128 + dd] = acc[fm][fn][jj];
      }
    }
  }
}

// reduce 8 chunks, normalize by 1/S, emit pre-swizzled bf16 kvT[n][m][dd']
__global__ void kv_reduce_swz(const float* __restrict__ part,
                              const float* __restrict__ colinv,
                              unsigned short* __restrict__ kvT) {
  int i = blockIdx.x * 256 + threadIdx.x;  // (n*64+m)*128+dd
  float s = 0.f;
#pragma unroll
  for (int c = 0; c < 8; ++c) s += part[(size_t)c * 524288 + i];
  int dd = i & 127;
  int m = (i >> 7) & 63;
  int n = i >> 13;
  float sc = colinv[(n >> 3) * 512 + (n & 7) * 64 + (dd & 63)];
  int gg = dd >> 3;
  int e = ((gg & 8) | ((gg ^ m) & 7)) * 8 + (dd & 7);
  kvT[(size_t)(i >> 7) * 128 + e] = f2bf(s * sc);
}

// ---------------------------------------------------------------------------
// Fused out pass, both terms (R8 known-good: vectorized Q loads, softmax via
// 8-lane-group shfl reduce, 1/sum folded into sin/cos scale).
// ---------------------------------------------------------------------------
__global__ __launch_bounds__(256) void out_fused(
    const unsigned short* __restrict__ Qp0, const unsigned short* __restrict__ Qp1,
    const unsigned short* __restrict__ kvT,
    const float* __restrict__ sintab, const float* __restrict__ costab,
    unsigned short* __restrict__ Yb) {
  __shared__ __align__(16) unsigned short q2s[64 * 128];
  __shared__ __align__(16) unsigned short kvs[2][64 * 128];
  const int tid = threadIdx.x;
  const int lc = blockIdx.x;
  const int n = blockIdx.y;
  const int b = n >> 3, h = n & 7;
  const int lane = tid & 63;
  const int w = tid >> 6;
  {
    const uint4* s0 = (const uint4*)(kvT + (size_t)n * 8192);
    const uint4* s1 = (const uint4*)(kvT + 524288 + (size_t)n * 8192);
    uint4* d0 = (uint4*)kvs[0];
    uint4* d1 = (uint4*)kvs[1];
#pragma unroll
    for (int i = 0; i < 4; ++i) {
      d0[tid + i * 256] = s0[tid + i * 256];
      d1[tid + i * 256] = s1[tid + i * 256];
    }
  }
  const int l0 = lc * 64;
  const int wr = w >> 1, wc = w & 1;
  const int lr = lane & 15;
  const int lk = (lane >> 4) * 8;
  const int rq = lane >> 4;
  f32x4 acc[2][2];
  acc[0][0] = acc[0][1] = acc[1][0] = acc[1][1] = (f32x4){0.f, 0.f, 0.f, 0.f};
#pragma unroll
  for (int t = 0; t < 2; ++t) {
    const unsigned short* Qp = t ? Qp1 : Qp0;
    if (t) __syncthreads();
#pragma unroll
    for (int i = 0; i < 2; ++i) {
      int idx = tid + i * 256;      // 0..511
      int row = idx >> 3;           // 0..63
      int g = idx & 7;
      uint4 q = *(const uint4*)(Qp + ((size_t)b * L_DIM + l0 + row) * 512 +
                                h * 64 + g * 8);
      float v[8];
      unpk8(q, v);
      float m8 = fmaxf(fmaxf(fmaxf(v[0], v[1]), fmaxf(v[2], v[3])),
                       fmaxf(fmaxf(v[4], v[5]), fmaxf(v[6], v[7])));
      m8 = fmaxf(m8, __shfl_xor(m8, 1));
      m8 = fmaxf(m8, __shfl_xor(m8, 2));
      m8 = fmaxf(m8, __shfl_xor(m8, 4));
      float e[8], s8;
#pragma unroll
      for (int k = 0; k < 8; ++k) e[k] = __expf(v[k] - m8);
      s8 = ((e[0] + e[1]) + (e[2] + e[3])) + ((e[4] + e[5]) + (e[6] + e[7]));
      s8 += __shfl_xor(s8, 1);
      s8 += __shfl_xor(s8, 2);
      s8 += __shfl_xor(s8, 4);
      float inv = 1.f / s8;
      int gl = l0 + row;
      float sn = sintab[gl] * inv;
      float cs = costab[gl] * inv;
      uint4 os, oc;
      os.x = pkbf(e[0] * sn, e[1] * sn); os.y = pkbf(e[2] * sn, e[3] * sn);
      os.z = pkbf(e[4] * sn, e[5] * sn); os.w = pkbf(e[6] * sn, e[7] * sn);
      oc.x = pkbf(e[0] * cs, e[1] * cs); oc.y = pkbf(e[2] * cs, e[3] * cs);
      oc.z = pkbf(e[4] * cs, e[5] * cs); oc.w = pkbf(e[6] * cs, e[7] * cs);
      *(uint4*)&q2s[swz128(row, g * 8)] = os;
      *(uint4*)&q2s[swz128(row, 64 + g * 8)] = oc;
    }
    __syncthreads();
#pragma unroll
    for (int ks = 0; ks < 4; ++ks) {
      int ke = ks * 32 + lk;
      bf16x8 av[2], bv[2];
#pragma unroll
      for (int fm = 0; fm < 2; ++fm)
        av[fm] = *(const bf16x8*)&q2s[swz128(wr * 32 + fm * 16 + lr, ke)];
#pragma unroll
      for (int fn = 0; fn < 2; ++fn)
        bv[fn] = *(const bf16x8*)&kvs[t][swz128(wc * 32 + fn * 16 + lr, ke)];
#pragma unroll
      for (int fm = 0; fm < 2; ++fm)
#pragma unroll
        for (int fn = 0; fn < 2; ++fn)
          acc[fm][fn] = __builtin_amdgcn_mfma_f32_16x16x32_bf16(av[fm], bv[fn],
                                                                acc[fm][fn], 0, 0, 0);
    }
  }
  __syncthreads();
  unsigned short* Os = q2s;  // 64 x (stride 72)
#pragma unroll
  for (int fn = 0; fn < 2; ++fn) {
    int col = wc * 32 + fn * 16 + lr;
#pragma unroll
    for (int fm = 0; fm < 2; ++fm) {
      int lrow = wr * 32 + fm * 16 + rq * 4;
#pragma unroll
      for (int jj = 0; jj < 4; ++jj)
        Os[(lrow + jj) * 72 + col] = f2bf(acc[fm][fn][jj]);
    }
  }
  __syncthreads();
#pragma unroll
  for (int i = 0; i < 2; ++i) {
    int idx = tid + i * 256;
    int row = idx >> 3, g = idx & 7;
    *(uint4*)(Yb + ((size_t)b * L_DIM + l0 + row) * 512 + h * 64 + g * 8) =
        *(const uint4*)&Os[row * 72 + g * 8];
  }
}

// ---------------------------------------------------------------------------
extern "C" void kernel_launch(void* const* d_in, const int* in_sizes, int n_in,
                              void* d_out, int out_size, void* d_ws, size_t ws_size,
                              hipStream_t stream) {
  const float* query = (const float*)d_in[0];
  const float* key   = (const float*)d_in[1];
  const float* value = (const float*)d_in[2];
  const float* Wq    = (const float*)d_in[3];
  const float* bq    = (const float*)d_in[4];
  const float* Wk    = (const float*)d_in[5];
  const float* bk    = (const float*)d_in[6];
  const float* Wv    = (const float*)d_in[7];
  const float* bv    = (const float*)d_in[8];
  const float* Wout  = (const float*)d_in[9];
  const float* bout  = (const float*)d_in[10];
  float* out = (float*)d_out;
  float* ws = (float*)d_ws;

  // workspace (fp32 slot units)
  const size_t F_PROJ0 = 0;                       // 32768x512 bf16 (t0)
  const size_t F_PROJ1 = F_PROJ0 + 8388608;       // 32768x512 bf16 (t1)
  const size_t F_VPB   = F_PROJ1 + 8388608;       // V proj bf16
  const size_t F_KVP   = F_VPB + 8388608;         // kv partials fp32 (aliases psum)
  const size_t F_KVT   = F_KVP + 4194304;         // kvT bf16, 2 terms
  const size_t F_XBUF  = F_KVT + 524288;          // bf16 input / attn-out (shared)
  const size_t F_WBF   = F_XBUF + 8388608;        // weights bf16
  const size_t F_CINV  = F_WBF + 786432;          // 1/S, 2 terms x 4096
  const size_t F_SIN   = F_CINV + 8192;
  const size_t F_COS   = F_SIN + 4096;
  const size_t TOTALF  = F_COS + 4096;
  if (ws_size < TOTALF * sizeof(float)) {
    fprintf(stderr, "kernel_launch: ws too small (%zu < %zu)\n", ws_size, TOTALF * 4);
    return;
  }
  unsigned short* proj0 = (unsigned short*)(ws + F_PROJ0);
  unsigned short* vpb   = (unsigned short*)(ws + F_VPB);
  float* kvpart = ws + F_KVP;
  unsigned short* kvT  = (unsigned short*)(ws + F_KVT);
  unsigned short* xbuf = (unsigned short*)(ws + F_XBUF);
  unsigned short* wbf  = (unsigned short*)(ws + F_WBF);
  float* cinv = ws + F_CINV;
  float* sintab = ws + F_SIN;
  float* costab = ws + F_COS;
  // psum aliases kvpart (1 MB of 16 MB region): consumed by colsum_reduce2
  // BEFORE any kv_mfma writes kvpart.
  float* psum = kvpart;
  const size_t WQ_O = 0, WK_O = 524288, WV_O = 1048576, WOUT_O = 1310720;

  sincos_kernel<<<16, 256, 0, stream>>>(sintab, costab);
  convf2b<<<256, 256, 0, stream>>>(Wq, wbf + WQ_O, 65536);
  convf2b<<<256, 256, 0, stream>>>(Wk, wbf + WK_O, 65536);
  convf2b<<<128, 256, 0, stream>>>(Wv, wbf + WV_O, 32768);
  convf2b<<<128, 256, 0, stream>>>(Wout, wbf + WOUT_O, 32768);

  // V projection: value -> bf16 (xbuf) -> GEMM -> vpb
  convf2b<<<2048, 256, 0, stream>>>(value, xbuf, 2097152);
  gemm_xwt<0, 2><<<1024, 256, 0, stream>>>(xbuf, wbf + WV_O, bv, vpb, nullptr);

  // K projections (both terms, N=1024): u = exp(logit) + fused column sums
  convf2b<<<2048, 256, 0, stream>>>(key, xbuf, 2097152);
  gemm_xwt<2, 3><<<2048, 256, 0, stream>>>(xbuf, wbf + WK_O, bk, proj0, psum);
  colsum_reduce2<<<32, 256, 0, stream>>>(psum, cinv);
  for (int t = 0; t < T_DIM; ++t) {
    unsigned short* projt = proj0 + (size_t)t * YHALF;
    kv_mfma<<<dim3(8, 64), 256, 0, stream>>>(projt, vpb, sintab, costab, kvpart);
    kv_reduce_swz<<<2048, 256, 0, stream>>>(kvpart, cinv + t * 4096,
                                            kvT + (size_t)t * 524288);
  }

  // Q projections (both terms, N=1024): plain bf16 store
  convf2b<<<2048, 256, 0, stream>>>(query, xbuf, 2097152);
  gemm_xwt<0, 3><<<2048, 256, 0, stream>>>(xbuf, wbf + WQ_O, bq, proj0, nullptr);
  // fused output accumulation (q-softmax inside) -> xbuf
  out_fused<<<dim3(64, 64), 256, 0, stream>>>(proj0, proj0 + YHALF, kvT,
                                              sintab, costab, xbuf);
  // final projection: bf16 A, fp32 out
  gemm_xwt<1, 2><<<1024, 256, 0, stream>>>(xbuf, wbf + WOUT_O, bout, out, nullptr);
}

// Round 15
// 316.018 us; speedup vs baseline: 1.3518x; 1.0001x over previous
//
#include <hip/hip_runtime.h>
#include <cstdio>

#define E_DIM 512
#define L_DIM 4096
#define B_DIM 8
#define H_DIM 8
#define T_DIM 2
#define M_ROWS 32768

typedef __attribute__((ext_vector_type(8))) __bf16 bf16x8;
typedef __attribute__((ext_vector_type(4))) float f32x4;

static __device__ __forceinline__ unsigned short f2bf(float f) {
  unsigned int u = __float_as_uint(f);
  return (unsigned short)((u + 0x7FFFu + ((u >> 16) & 1u)) >> 16);
}
static __device__ __forceinline__ unsigned int pkbf(float lo, float hi) {
  return (unsigned int)f2bf(lo) | ((unsigned int)f2bf(hi) << 16);
}
static __device__ __forceinline__ float bf2f(unsigned short u) {
  return __uint_as_float((unsigned int)u << 16);
}
static __device__ __forceinline__ void unpk8(uint4 u, float* f) {
  f[0] = bf2f((unsigned short)u.x); f[1] = bf2f((unsigned short)(u.x >> 16));
  f[2] = bf2f((unsigned short)u.y); f[3] = bf2f((unsigned short)(u.y >> 16));
  f[4] = bf2f((unsigned short)u.z); f[5] = bf2f((unsigned short)(u.z >> 16));
  f[6] = bf2f((unsigned short)u.w); f[7] = bf2f((unsigned short)(u.w >> 16));
}
// XOR swizzle at 8-elem (16B) granules
static __device__ __forceinline__ int swz64(int row, int e) {
  return row * 64 + ((((e >> 3) ^ row) & 7) << 3) + (e & 7);
}
static __device__ __forceinline__ int swz128(int row, int e) {
  return row * 128 + ((((e >> 3) ^ row) & 7) << 3) + ((e >> 3) & 8) * 8 + (e & 7);
}
// async global->LDS, 16B per lane; LDS dest = wave-uniform base + lane*16
static __device__ __forceinline__ void gl_lds16(const unsigned short* g,
                                                unsigned short* l) {
  __builtin_amdgcn_global_load_lds(
      (const __attribute__((address_space(1))) unsigned int*)g,
      (__attribute__((address_space(3))) unsigned int*)l, 16, 0, 0);
}

// ---------------------------------------------------------------------------
__global__ void sincos_kernel(float* __restrict__ sintab, float* __restrict__ costab) {
  int i = blockIdx.x * blockDim.x + threadIdx.x;
  if (i < L_DIM) {
    float idx = 1.57079632679489662f * (float)(i + 1) / (float)L_DIM;
    sintab[i] = sinf(idx);
    costab[i] = cosf(idx);
  }
}

__global__ void convf2b(const float* __restrict__ src, unsigned short* __restrict__ dst,
                        int n8) {
  for (int i = blockIdx.x * blockDim.x + threadIdx.x; i < n8; i += gridDim.x * blockDim.x) {
    float4 a = *(const float4*)(src + (size_t)i * 8);
    float4 b = *(const float4*)(src + (size_t)i * 8 + 4);
    uint4 o;
    o.x = pkbf(a.x, a.y); o.y = pkbf(a.z, a.w);
    o.z = pkbf(b.x, b.y); o.w = pkbf(b.z, b.w);
    *(uint4*)(dst + (size_t)i * 8) = o;
  }
}

// ---------------------------------------------------------------------------
// Y[M][N] = X[M][512] @ W[N][512]^T + bias[N]; N = 512<<(NBL2-2).
// MODE 0: plain bf16 store (split buffers at n=512, u16 stride YHALF)
// MODE 1: fp32 store
// MODE 2: u = exp(acc+bias) bf16 store + per-mtile column SUMS -> psum (K path)
// Main loop: double-buffered global_load_lds (linear dest, inverse-swz source).
// __launch_bounds__(256,2): LDS caps at 2 blocks/CU; let regalloc use VGPRs
// (R10 lesson: default bound gave 88 VGPR -> main-loop spill; R12 lesson:
// reg-staged fp32 A both spills and breaks coalescing — keep bf16-only A).
// ---------------------------------------------------------------------------
#define YHALF 16777216
template <int MODE, int NBL2>
__global__ __launch_bounds__(256, 2) void gemm_xwt(
    const unsigned short* __restrict__ X, const unsigned short* __restrict__ W,
    const float* __restrict__ bias, void* __restrict__ Yv,
    float* __restrict__ psum) {
  __shared__ __align__(16) unsigned short smem[32768];  // 2 x (As 8192 + Bs 8192)
  __shared__ float sf2[256];
  const int tid = threadIdx.x;
  const int id = blockIdx.x;
  const int j = id >> 3;
  const int mb = (id & 7) * 32 + (j >> NBL2);
  const int nb = j & ((1 << NBL2) - 1);
  const int m0 = mb * 128, n0 = nb * 128;
  const int lane = tid & 63;
  const int w = tid >> 6;
  const int wr = w >> 1, wc = w & 1;
  const int lr = lane & 15;
  const int lk = (lane >> 4) * 8;
  const int rq = lane >> 4;
  const int srow = lane >> 3;                 // 0..7
  const int gsrc8 = ((lane & 7) ^ srow) * 8;  // inverse-swizzled source granule
  f32x4 acc[4][4];
#pragma unroll
  for (int i = 0; i < 4; ++i)
#pragma unroll
    for (int jj = 0; jj < 4; ++jj) acc[i][jj] = (f32x4){0.f, 0.f, 0.f, 0.f};

  // prologue: stage tile 0 into buffer 0
#pragma unroll
  for (int i = 0; i < 4; ++i) {
    int rb = w * 32 + i * 8;
    gl_lds16(X + (size_t)(m0 + rb + srow) * 512 + gsrc8, &smem[rb * 64]);
    gl_lds16(W + (size_t)(n0 + rb + srow) * 512 + gsrc8, &smem[8192 + rb * 64]);
  }
  __syncthreads();

#pragma unroll
  for (int step = 0; step < 8; ++step) {
    const int cur = step & 1;
    if (step < 7) {
      unsigned short* Ab = smem + (cur ^ 1) * 16384;
      const int kn = (step + 1) * 64;
#pragma unroll
      for (int i = 0; i < 4; ++i) {
        int rb = w * 32 + i * 8;
        gl_lds16(X + (size_t)(m0 + rb + srow) * 512 + kn + gsrc8, &Ab[rb * 64]);
        gl_lds16(W + (size_t)(n0 + rb + srow) * 512 + kn + gsrc8,
                 &Ab[8192 + rb * 64]);
      }
    }
    const unsigned short* As = smem + cur * 16384;
    const unsigned short* Bs = As + 8192;
#pragma unroll
    for (int kk = 0; kk < 2; ++kk) {
      bf16x8 av[4], bv[4];
      int ke = kk * 32 + lk;
#pragma unroll
      for (int fm = 0; fm < 4; ++fm)
        av[fm] = *(const bf16x8*)&As[swz64(wr * 64 + fm * 16 + lr, ke)];
#pragma unroll
      for (int fn = 0; fn < 4; ++fn)
        bv[fn] = *(const bf16x8*)&Bs[swz64(wc * 64 + fn * 16 + lr, ke)];
#pragma unroll
      for (int fm = 0; fm < 4; ++fm)
#pragma unroll
        for (int fn = 0; fn < 4; ++fn)
          acc[fm][fn] = __builtin_amdgcn_mfma_f32_16x16x32_bf16(av[fm], bv[fn],
                                                                acc[fm][fn], 0, 0, 0);
    }
    __syncthreads();
  }

  // ---- epilogues ----
  if (MODE == 0 || MODE == 2) {
    unsigned short* Cs = smem;  // 128 x (stride 136) bf16 tile
    if (MODE == 0) {
#pragma unroll
      for (int fn = 0; fn < 4; ++fn) {
        int col = wc * 64 + fn * 16 + lr;
        float bb = bias[n0 + col];
#pragma unroll
        for (int fm = 0; fm < 4; ++fm) {
          int row = wr * 64 + fm * 16 + rq * 4;
#pragma unroll
          for (int jj = 0; jj < 4; ++jj)
            Cs[(row + jj) * 136 + col] = f2bf(acc[fm][fn][jj] + bb);
        }
      }
    } else {
      // MODE 2: u = exp(logit); per-column sums over this tile's 128 rows
#pragma unroll
      for (int fn = 0; fn < 4; ++fn) {
        int col = wc * 64 + fn * 16 + lr;
        float bb = bias[n0 + col];
        float S = 0.f;
#pragma unroll
        for (int fm = 0; fm < 4; ++fm) {
          int row = wr * 64 + fm * 16 + rq * 4;
#pragma unroll
          for (int jj = 0; jj < 4; ++jj) {
            float u = __expf(acc[fm][fn][jj] + bb);
            S += u;
            Cs[(row + jj) * 136 + col] = f2bf(u);
          }
        }
        S += __shfl_xor(S, 16);
        S += __shfl_xor(S, 32);
        if (rq == 0) sf2[wr * 128 + col] = S;
      }
    }
    __syncthreads();
    if (MODE == 2 && tid < 128) {
      float S = sf2[tid] + sf2[128 + tid];
      psum[(size_t)(m0 >> 7) * (128 << NBL2) + n0 + tid] = S;
    }
    unsigned short* Yb = (unsigned short*)Yv + (size_t)(n0 >> 9) * YHALF;
    const int nc = n0 & 511;
#pragma unroll
    for (int i = 0; i < 8; ++i) {
      int idx = tid + i * 256;     // 0..2047
      int row = idx >> 4, g = idx & 15;
      *(uint4*)(Yb + (size_t)(m0 + row) * 512 + nc + g * 8) =
          *(const uint4*)&Cs[row * 136 + g * 8];
    }
  } else {  // MODE 1: fp32 store
    float* Cf = (float*)smem;  // 64 x (stride 132)
    float* Yf = (float*)Yv;
#pragma unroll
    for (int p = 0; p < 2; ++p) {
      if (p) __syncthreads();
      if (wr == p) {
#pragma unroll
        for (int fn = 0; fn < 4; ++fn) {
          int col = wc * 64 + fn * 16 + lr;
          float bb = bias[n0 + col];
#pragma unroll
          for (int fm = 0; fm < 4; ++fm) {
            int lrow = fm * 16 + rq * 4;
#pragma unroll
            for (int jj = 0; jj < 4; ++jj)
              Cf[(lrow + jj) * 132 + col] = acc[fm][fn][jj] + bb;
          }
        }
      }
      __syncthreads();
#pragma unroll
      for (int i = 0; i < 8; ++i) {
        int idx = tid + i * 256;
        int row = idx >> 5, g = idx & 31;
        *(float4*)(Yf + (size_t)(m0 + p * 64 + row) * 512 + n0 + g * 4) =
            *(const float4*)&Cf[row * 132 + g * 4];
      }
    }
  }
}

// ---------------------------------------------------------------------------
// column-sum reduce over the 32 mtiles of each b -> 1/S ; both terms in one
// launch (grid 32: block>>4 selects term)
// ---------------------------------------------------------------------------
__global__ void colsum_reduce2(const float* __restrict__ psum,
                               float* __restrict__ colinv) {
  int t = blockIdx.x >> 4;
  int i = (blockIdx.x & 15) * 256 + threadIdx.x;  // b*512+f, 0..4095
  int b = i >> 9, f = i & 511;
  float S = 0.f;
#pragma unroll
  for (int c = 0; c < 32; ++c)
    S += psum[(size_t)(b * 32 + c) * 1024 + t * 512 + f];
  colinv[t * 4096 + i] = 1.f / S;
}

// ---------------------------------------------------------------------------
// kv partials via MFMA: C[d][ncol] = sum_s u[s][d]*B[s][ncol], B=[v*sin|v*cos]
// u is pre-exp'd bf16 (no front-end math). grid (8 s-chunks, 64 n), 256 thr.
// ---------------------------------------------------------------------------
__global__ __launch_bounds__(256) void kv_mfma(
    const unsigned short* __restrict__ Up, const unsigned short* __restrict__ Vpb,
    const float* __restrict__ sintab, const float* __restrict__ costab,
    float* __restrict__ kvpart) {
  __shared__ __align__(16) unsigned short kT[64 * 64];
  __shared__ __align__(16) unsigned short vT[128 * 64];
  const int tid = threadIdx.x;
  const int chunk = blockIdx.x;
  const int n = blockIdx.y;
  const int b = n >> 3, h = n & 7;
  const int lane = tid & 63;
  const int w = tid >> 6;
  const int lr = lane & 15;
  const int lk = (lane >> 4) * 8;
  const int sp = tid & 31;
  const int g = tid >> 5;
  f32x4 acc[4][2];
#pragma unroll
  for (int i = 0; i < 4; ++i) {
    acc[i][0] = (f32x4){0.f, 0.f, 0.f, 0.f};
    acc[i][1] = (f32x4){0.f, 0.f, 0.f, 0.f};
  }

  for (int st = 0; st < 8; ++st) {
    int sA = chunk * 512 + st * 64 + 2 * sp;
    const unsigned short* kp = Up + ((size_t)b * L_DIM + sA) * 512 + h * 64 + g * 8;
    uint4 ka = *(const uint4*)kp;
    uint4 kb = *(const uint4*)(kp + 512);
    int vr = ((sA >> 9) << 12) + ((sA & 511) << 3) + b;
    const unsigned short* vp = Vpb + (size_t)vr * 512 + h * 64 + g * 8;
    uint4 v0 = *(const uint4*)vp;
    uint4 v1 = *(const uint4*)(vp + 8 * 512);
    unsigned short ua[8], ub[8];
    *(uint4*)ua = ka;
    *(uint4*)ub = kb;
    float vA[8], vB[8];
    unpk8(v0, vA);
    unpk8(v1, vB);
    float sS = sintab[sA], sC = costab[sA];
    float tS = sintab[sA + 1], tC = costab[sA + 1];
    __syncthreads();  // previous iteration's MFMA LDS reads done
#pragma unroll
    for (int i = 0; i < 8; ++i) {
      int d = g * 8 + i;
      *(unsigned int*)&kT[swz64(d, 2 * sp)] =
          (unsigned int)ua[i] | ((unsigned int)ub[i] << 16);
    }
#pragma unroll
    for (int i = 0; i < 8; ++i) {
      int m = g * 8 + i;
      *(unsigned int*)&vT[swz64(m, 2 * sp)] = pkbf(vA[i] * sS, vB[i] * tS);
      *(unsigned int*)&vT[swz64(64 + m, 2 * sp)] = pkbf(vA[i] * sC, vB[i] * tC);
    }
    __syncthreads();
#pragma unroll
    for (int kk = 0; kk < 2; ++kk) {
      int ke = kk * 32 + lk;
      bf16x8 av[4], bv[2];
#pragma unroll
      for (int fm = 0; fm < 4; ++fm)
        av[fm] = *(const bf16x8*)&kT[swz64(fm * 16 + lr, ke)];
#pragma unroll
      for (int fn = 0; fn < 2; ++fn)
        bv[fn] = *(const bf16x8*)&vT[swz64(w * 32 + fn * 16 + lr, ke)];
#pragma unroll
      for (int fm = 0; fm < 4; ++fm)
#pragma unroll
        for (int fn = 0; fn < 2; ++fn)
          acc[fm][fn] = __builtin_amdgcn_mfma_f32_16x16x32_bf16(av[fm], bv[fn],
                                                                acc[fm][fn], 0, 0, 0);
    }
  }
  const int rq = lane >> 4;
#pragma unroll
  for (int fn = 0; fn < 2; ++fn) {
    int ncol = w * 32 + fn * 16 + lr;
    int m = ncol & 63;
    int ddbase = (ncol >> 6) * 64;
#pragma unroll
    for (int fm = 0; fm < 4; ++fm) {
#pragma unroll
      for (int jj = 0; jj < 4; ++jj) {
        int dd = ddbase + fm * 16 + rq * 4 + jj;
        kvpart[(((size_t)chunk * 64 + n) * 64 + m) * 128 + dd] = acc[fm][fn][jj];
      }
    }
  }
}

// reduce 8 chunks, normalize by 1/S, emit pre-swizzled bf16 kvT[n][m][dd']
__global__ void kv_reduce_swz(const float* __restrict__ part,
                              const float* __restrict__ colinv,
                              unsigned short* __restrict__ kvT) {
  int i = blockIdx.x * 256 + threadIdx.x;  // (n*64+m)*128+dd
  float s = 0.f;
#pragma unroll
  for (int c = 0; c < 8; ++c) s += part[(size_t)c * 524288 + i];
  int dd = i & 127;
  int m = (i >> 7) & 63;
  int n = i >> 13;
  float sc = colinv[(n >> 3) * 512 + (n & 7) * 64 + (dd & 63)];
  int gg = dd >> 3;
  int e = ((gg & 8) | ((gg ^ m) & 7)) * 8 + (dd & 7);
  kvT[(size_t)(i >> 7) * 128 + e] = f2bf(s * sc);
}

// ---------------------------------------------------------------------------
// Fused out pass, both terms (R8 known-good: vectorized Q loads, softmax via
// 8-lane-group shfl reduce, 1/sum folded into sin/cos scale).
// ---------------------------------------------------------------------------
__global__ __launch_bounds__(256) void out_fused(
    const unsigned short* __restrict__ Qp0, const unsigned short* __restrict__ Qp1,
    const unsigned short* __restrict__ kvT,
    const float* __restrict__ sintab, const float* __restrict__ costab,
    unsigned short* __restrict__ Yb) {
  __shared__ __align__(16) unsigned short q2s[64 * 128];
  __shared__ __align__(16) unsigned short kvs[2][64 * 128];
  const int tid = threadIdx.x;
  const int lc = blockIdx.x;
  const int n = blockIdx.y;
  const int b = n >> 3, h = n & 7;
  const int lane = tid & 63;
  const int w = tid >> 6;
  {
    const uint4* s0 = (const uint4*)(kvT + (size_t)n * 8192);
    const uint4* s1 = (const uint4*)(kvT + 524288 + (size_t)n * 8192);
    uint4* d0 = (uint4*)kvs[0];
    uint4* d1 = (uint4*)kvs[1];
#pragma unroll
    for (int i = 0; i < 4; ++i) {
      d0[tid + i * 256] = s0[tid + i * 256];
      d1[tid + i * 256] = s1[tid + i * 256];
    }
  }
  const int l0 = lc * 64;
  const int wr = w >> 1, wc = w & 1;
  const int lr = lane & 15;
  const int lk = (lane >> 4) * 8;
  const int rq = lane >> 4;
  f32x4 acc[2][2];
  acc[0][0] = acc[0][1] = acc[1][0] = acc[1][1] = (f32x4){0.f, 0.f, 0.f, 0.f};
#pragma unroll
  for (int t = 0; t < 2; ++t) {
    const unsigned short* Qp = t ? Qp1 : Qp0;
    if (t) __syncthreads();
#pragma unroll
    for (int i = 0; i < 2; ++i) {
      int idx = tid + i * 256;      // 0..511
      int row = idx >> 3;           // 0..63
      int g = idx & 7;
      uint4 q = *(const uint4*)(Qp + ((size_t)b * L_DIM + l0 + row) * 512 +
                                h * 64 + g * 8);
      float v[8];
      unpk8(q, v);
      float m8 = fmaxf(fmaxf(fmaxf(v[0], v[1]), fmaxf(v[2], v[3])),
                       fmaxf(fmaxf(v[4], v[5]), fmaxf(v[6], v[7])));
      m8 = fmaxf(m8, __shfl_xor(m8, 1));
      m8 = fmaxf(m8, __shfl_xor(m8, 2));
      m8 = fmaxf(m8, __shfl_xor(m8, 4));
      float e[8], s8;
#pragma unroll
      for (int k = 0; k < 8; ++k) e[k] = __expf(v[k] - m8);
      s8 = ((e[0] + e[1]) + (e[2] + e[3])) + ((e[4] + e[5]) + (e[6] + e[7]));
      s8 += __shfl_xor(s8, 1);
      s8 += __shfl_xor(s8, 2);
      s8 += __shfl_xor(s8, 4);
      float inv = 1.f / s8;
      int gl = l0 + row;
      float sn = sintab[gl] * inv;
      float cs = costab[gl] * inv;
      uint4 os, oc;
      os.x = pkbf(e[0] * sn, e[1] * sn); os.y = pkbf(e[2] * sn, e[3] * sn);
      os.z = pkbf(e[4] * sn, e[5] * sn); os.w = pkbf(e[6] * sn, e[7] * sn);
      oc.x = pkbf(e[0] * cs, e[1] * cs); oc.y = pkbf(e[2] * cs, e[3] * cs);
      oc.z = pkbf(e[4] * cs, e[5] * cs); oc.w = pkbf(e[6] * cs, e[7] * cs);
      *(uint4*)&q2s[swz128(row, g * 8)] = os;
      *(uint4*)&q2s[swz128(row, 64 + g * 8)] = oc;
    }
    __syncthreads();
#pragma unroll
    for (int ks = 0; ks < 4; ++ks) {
      int ke = ks * 32 + lk;
      bf16x8 av[2], bv[2];
#pragma unroll
      for (int fm = 0; fm < 2; ++fm)
        av[fm] = *(const bf16x8*)&q2s[swz128(wr * 32 + fm * 16 + lr, ke)];
#pragma unroll
      for (int fn = 0; fn < 2; ++fn)
        bv[fn] = *(const bf16x8*)&kvs[t][swz128(wc * 32 + fn * 16 + lr, ke)];
#pragma unroll
      for (int fm = 0; fm < 2; ++fm)
#pragma unroll
        for (int fn = 0; fn < 2; ++fn)
          acc[fm][fn] = __builtin_amdgcn_mfma_f32_16x16x32_bf16(av[fm], bv[fn],
                                                                acc[fm][fn], 0, 0, 0);
    }
  }
  __syncthreads();
  unsigned short* Os = q2s;  // 64 x (stride 72)
#pragma unroll
  for (int fn = 0; fn < 2; ++fn) {
    int col = wc * 32 + fn * 16 + lr;
#pragma unroll
    for (int fm = 0; fm < 2; ++fm) {
      int lrow = wr * 32 + fm * 16 + rq * 4;
#pragma unroll
      for (int jj = 0; jj < 4; ++jj)
        Os[(lrow + jj) * 72 + col] = f2bf(acc[fm][fn][jj]);
    }
  }
  __syncthreads();
#pragma unroll
  for (int i = 0; i < 2; ++i) {
    int idx = tid + i * 256;
    int row = idx >> 3, g = idx & 7;
    *(uint4*)(Yb + ((size_t)b * L_DIM + l0 + row) * 512 + h * 64 + g * 8) =
        *(const uint4*)&Os[row * 72 + g * 8];
  }
}

// ---------------------------------------------------------------------------
extern "C" void kernel_launch(void* const* d_in, const int* in_sizes, int n_in,
                              void* d_out, int out_size, void* d_ws, size_t ws_size,
                              hipStream_t stream) {
  const float* query = (const float*)d_in[0];
  const float* key   = (const float*)d_in[1];
  const float* value = (const float*)d_in[2];
  const float* Wq    = (const float*)d_in[3];
  const float* bq    = (const float*)d_in[4];
  const float* Wk    = (const float*)d_in[5];
  const float* bk    = (const float*)d_in[6];
  const float* Wv    = (const float*)d_in[7];
  const float* bv    = (const float*)d_in[8];
  const float* Wout  = (const float*)d_in[9];
  const float* bout  = (const float*)d_in[10];
  float* out = (float*)d_out;
  float* ws = (float*)d_ws;

  // workspace (fp32 slot units)
  const size_t F_PROJ0 = 0;                       // 32768x512 bf16 (t0)
  const size_t F_PROJ1 = F_PROJ0 + 8388608;       // 32768x512 bf16 (t1)
  const size_t F_VPB   = F_PROJ1 + 8388608;       // V proj bf16
  const size_t F_KVP   = F_VPB + 8388608;         // kv partials fp32 (aliases psum)
  const size_t F_KVT   = F_KVP + 4194304;         // kvT bf16, 2 terms
  const size_t F_XBUF  = F_KVT + 524288;          // bf16 input / attn-out (shared)
  const size_t F_WBF   = F_XBUF + 8388608;        // weights bf16
  const size_t F_CINV  = F_WBF + 786432;          // 1/S, 2 terms x 4096
  const size_t F_SIN   = F_CINV + 8192;
  const size_t F_COS   = F_SIN + 4096;
  const size_t TOTALF  = F_COS + 4096;
  if (ws_size < TOTALF * sizeof(float)) {
    fprintf(stderr, "kernel_launch: ws too small (%zu < %zu)\n", ws_size, TOTALF * 4);
    return;
  }
  unsigned short* proj0 = (unsigned short*)(ws + F_PROJ0);
  unsigned short* vpb   = (unsigned short*)(ws + F_VPB);
  float* kvpart = ws + F_KVP;
  unsigned short* kvT  = (unsigned short*)(ws + F_KVT);
  unsigned short* xbuf = (unsigned short*)(ws + F_XBUF);
  unsigned short* wbf  = (unsigned short*)(ws + F_WBF);
  float* cinv = ws + F_CINV;
  float* sintab = ws + F_SIN;
  float* costab = ws + F_COS;
  // psum aliases kvpart (1 MB of 16 MB region): consumed by colsum_reduce2
  // BEFORE any kv_mfma writes kvpart.
  float* psum = kvpart;
  const size_t WQ_O = 0, WK_O = 524288, WV_O = 1048576, WOUT_O = 1310720;

  sincos_kernel<<<16, 256, 0, stream>>>(sintab, costab);
  convf2b<<<256, 256, 0, stream>>>(Wq, wbf + WQ_O, 65536);
  convf2b<<<256, 256, 0, stream>>>(Wk, wbf + WK_O, 65536);
  convf2b<<<128, 256, 0, stream>>>(Wv, wbf + WV_O, 32768);
  convf2b<<<128, 256, 0, stream>>>(Wout, wbf + WOUT_O, 32768);

  // V projection: value -> bf16 (xbuf) -> GEMM -> vpb
  convf2b<<<2048, 256, 0, stream>>>(value, xbuf, 2097152);
  gemm_xwt<0, 2><<<1024, 256, 0, stream>>>(xbuf, wbf + WV_O, bv, vpb, nullptr);

  // K projections (both terms, N=1024): u = exp(logit) + fused column sums
  convf2b<<<2048, 256, 0, stream>>>(key, xbuf, 2097152);
  gemm_xwt<2, 3><<<2048, 256, 0, stream>>>(xbuf, wbf + WK_O, bk, proj0, psum);
  colsum_reduce2<<<32, 256, 0, stream>>>(psum, cinv);
  for (int t = 0; t < T_DIM; ++t) {
    unsigned short* projt = proj0 + (size_t)t * YHALF;
    kv_mfma<<<dim3(8, 64), 256, 0, stream>>>(projt, vpb, sintab, costab, kvpart);
    kv_reduce_swz<<<2048, 256, 0, stream>>>(kvpart, cinv + t * 4096,
                                            kvT + (size_t)t * 524288);
  }

  // Q projections (both terms, N=1024): plain bf16 store
  convf2b<<<2048, 256, 0, stream>>>(query, xbuf, 2097152);
  gemm_xwt<0, 3><<<2048, 256, 0, stream>>>(xbuf, wbf + WQ_O, bq, proj0, nullptr);
  // fused output accumulation (q-softmax inside) -> xbuf
  out_fused<<<dim3(64, 64), 256, 0, stream>>>(proj0, proj0 + YHALF, kvT,
                                              sintab, costab, xbuf);
  // final projection: bf16 A, fp32 out
  gemm_xwt<1, 2><<<1024, 256, 0, stream>>>(xbuf, wbf + WOUT_O, bout, out, nullptr);
}

// Round 16
// 304.080 us; speedup vs baseline: 1.4048x; 1.0393x over previous
//
#include <hip/hip_runtime.h>
#include <cstdio>

#define E_DIM 512
#define L_DIM 4096
#define B_DIM 8
#define H_DIM 8
#define T_DIM 2
#define M_ROWS 32768

typedef __attribute__((ext_vector_type(8))) __bf16 bf16x8;
typedef __attribute__((ext_vector_type(4))) float f32x4;

static __device__ __forceinline__ unsigned short f2bf(float f) {
  unsigned int u = __float_as_uint(f);
  return (unsigned short)((u + 0x7FFFu + ((u >> 16) & 1u)) >> 16);
}
static __device__ __forceinline__ unsigned int pkbf(float lo, float hi) {
  return (unsigned int)f2bf(lo) | ((unsigned int)f2bf(hi) << 16);
}
static __device__ __forceinline__ float bf2f(unsigned short u) {
  return __uint_as_float((unsigned int)u << 16);
}
static __device__ __forceinline__ void unpk8(uint4 u, float* f) {
  f[0] = bf2f((unsigned short)u.x); f[1] = bf2f((unsigned short)(u.x >> 16));
  f[2] = bf2f((unsigned short)u.y); f[3] = bf2f((unsigned short)(u.y >> 16));
  f[4] = bf2f((unsigned short)u.z); f[5] = bf2f((unsigned short)(u.z >> 16));
  f[6] = bf2f((unsigned short)u.w); f[7] = bf2f((unsigned short)(u.w >> 16));
}
// XOR swizzle at 8-elem (16B) granules
static __device__ __forceinline__ int swz64(int row, int e) {
  return row * 64 + ((((e >> 3) ^ row) & 7) << 3) + (e & 7);
}
static __device__ __forceinline__ int swz128(int row, int e) {
  return row * 128 + ((((e >> 3) ^ row) & 7) << 3) + ((e >> 3) & 8) * 8 + (e & 7);
}
// async global->LDS, 16B per lane; LDS dest = wave-uniform base + lane*16
static __device__ __forceinline__ void gl_lds16(const unsigned short* g,
                                                unsigned short* l) {
  __builtin_amdgcn_global_load_lds(
      (const __attribute__((address_space(1))) unsigned int*)g,
      (__attribute__((address_space(3))) unsigned int*)l, 16, 0, 0);
}

// ---------------------------------------------------------------------------
// Fused prologue: blocks 0..767 convert the 4 weight tensors (contiguous in
// wbf: Wq|Wk|Wv|Wout = 196608 groups of 8), blocks 768..783 fill sin/cos.
// Replaces 5 tiny dispatches (launch/tail overhead consolidation).
// ---------------------------------------------------------------------------
__global__ void prep_kernel(const float* __restrict__ Wq, const float* __restrict__ Wk,
                            const float* __restrict__ Wv, const float* __restrict__ Wout,
                            unsigned short* __restrict__ wbf,
                            float* __restrict__ sintab, float* __restrict__ costab) {
  int blk = blockIdx.x;
  if (blk < 768) {
    int i8 = blk * 256 + threadIdx.x;  // 0..196607
    const float* src;
    if (i8 < 65536) src = Wq + (size_t)i8 * 8;
    else if (i8 < 131072) src = Wk + (size_t)(i8 - 65536) * 8;
    else if (i8 < 163840) src = Wv + (size_t)(i8 - 131072) * 8;
    else src = Wout + (size_t)(i8 - 163840) * 8;
    float4 a = *(const float4*)src;
    float4 b = *(const float4*)(src + 4);
    uint4 o;
    o.x = pkbf(a.x, a.y); o.y = pkbf(a.z, a.w);
    o.z = pkbf(b.x, b.y); o.w = pkbf(b.z, b.w);
    *(uint4*)(wbf + (size_t)i8 * 8) = o;
  } else {
    int i = (blk - 768) * 256 + threadIdx.x;  // 0..4095
    float idx = 1.57079632679489662f * (float)(i + 1) / (float)L_DIM;
    sintab[i] = sinf(idx);
    costab[i] = cosf(idx);
  }
}

__global__ void convf2b(const float* __restrict__ src, unsigned short* __restrict__ dst,
                        int n8) {
  for (int i = blockIdx.x * blockDim.x + threadIdx.x; i < n8; i += gridDim.x * blockDim.x) {
    float4 a = *(const float4*)(src + (size_t)i * 8);
    float4 b = *(const float4*)(src + (size_t)i * 8 + 4);
    uint4 o;
    o.x = pkbf(a.x, a.y); o.y = pkbf(a.z, a.w);
    o.z = pkbf(b.x, b.y); o.w = pkbf(b.z, b.w);
    *(uint4*)(dst + (size_t)i * 8) = o;
  }
}

// ---------------------------------------------------------------------------
// Y[M][N] = X[M][512] @ W[N][512]^T + bias[N]; N = 512<<(NBL2-2).
// MODE 0: plain bf16 store (split buffers at n=512, u16 stride YHALF)
// MODE 1: fp32 store
// MODE 2: u = exp(acc+bias) bf16 store + per-mtile column SUMS -> psum (K path)
// Main loop: double-buffered global_load_lds (linear dest, inverse-swz source).
// __launch_bounds__(256,2): LDS caps at 2 blocks/CU; let regalloc use VGPRs
// (R10 lesson: default bound gave 88 VGPR -> main-loop spill; R12 lesson:
// reg-staged fp32 A both spills and breaks coalescing — keep bf16-only A).
// ---------------------------------------------------------------------------
#define YHALF 16777216
template <int MODE, int NBL2>
__global__ __launch_bounds__(256, 2) void gemm_xwt(
    const unsigned short* __restrict__ X, const unsigned short* __restrict__ W,
    const float* __restrict__ bias, void* __restrict__ Yv,
    float* __restrict__ psum) {
  __shared__ __align__(16) unsigned short smem[32768];  // 2 x (As 8192 + Bs 8192)
  __shared__ float sf2[256];
  const int tid = threadIdx.x;
  const int id = blockIdx.x;
  const int j = id >> 3;
  const int mb = (id & 7) * 32 + (j >> NBL2);
  const int nb = j & ((1 << NBL2) - 1);
  const int m0 = mb * 128, n0 = nb * 128;
  const int lane = tid & 63;
  const int w = tid >> 6;
  const int wr = w >> 1, wc = w & 1;
  const int lr = lane & 15;
  const int lk = (lane >> 4) * 8;
  const int rq = lane >> 4;
  const int srow = lane >> 3;                 // 0..7
  const int gsrc8 = ((lane & 7) ^ srow) * 8;  // inverse-swizzled source granule
  f32x4 acc[4][4];
#pragma unroll
  for (int i = 0; i < 4; ++i)
#pragma unroll
    for (int jj = 0; jj < 4; ++jj) acc[i][jj] = (f32x4){0.f, 0.f, 0.f, 0.f};

  // prologue: stage tile 0 into buffer 0
#pragma unroll
  for (int i = 0; i < 4; ++i) {
    int rb = w * 32 + i * 8;
    gl_lds16(X + (size_t)(m0 + rb + srow) * 512 + gsrc8, &smem[rb * 64]);
    gl_lds16(W + (size_t)(n0 + rb + srow) * 512 + gsrc8, &smem[8192 + rb * 64]);
  }
  __syncthreads();

#pragma unroll
  for (int step = 0; step < 8; ++step) {
    const int cur = step & 1;
    if (step < 7) {
      unsigned short* Ab = smem + (cur ^ 1) * 16384;
      const int kn = (step + 1) * 64;
#pragma unroll
      for (int i = 0; i < 4; ++i) {
        int rb = w * 32 + i * 8;
        gl_lds16(X + (size_t)(m0 + rb + srow) * 512 + kn + gsrc8, &Ab[rb * 64]);
        gl_lds16(W + (size_t)(n0 + rb + srow) * 512 + kn + gsrc8,
                 &Ab[8192 + rb * 64]);
      }
    }
    const unsigned short* As = smem + cur * 16384;
    const unsigned short* Bs = As + 8192;
#pragma unroll
    for (int kk = 0; kk < 2; ++kk) {
      bf16x8 av[4], bv[4];
      int ke = kk * 32 + lk;
#pragma unroll
      for (int fm = 0; fm < 4; ++fm)
        av[fm] = *(const bf16x8*)&As[swz64(wr * 64 + fm * 16 + lr, ke)];
#pragma unroll
      for (int fn = 0; fn < 4; ++fn)
        bv[fn] = *(const bf16x8*)&Bs[swz64(wc * 64 + fn * 16 + lr, ke)];
#pragma unroll
      for (int fm = 0; fm < 4; ++fm)
#pragma unroll
        for (int fn = 0; fn < 4; ++fn)
          acc[fm][fn] = __builtin_amdgcn_mfma_f32_16x16x32_bf16(av[fm], bv[fn],
                                                                acc[fm][fn], 0, 0, 0);
    }
    __syncthreads();
  }

  // ---- epilogues ----
  if (MODE == 0 || MODE == 2) {
    unsigned short* Cs = smem;  // 128 x (stride 136) bf16 tile
    if (MODE == 0) {
#pragma unroll
      for (int fn = 0; fn < 4; ++fn) {
        int col = wc * 64 + fn * 16 + lr;
        float bb = bias[n0 + col];
#pragma unroll
        for (int fm = 0; fm < 4; ++fm) {
          int row = wr * 64 + fm * 16 + rq * 4;
#pragma unroll
          for (int jj = 0; jj < 4; ++jj)
            Cs[(row + jj) * 136 + col] = f2bf(acc[fm][fn][jj] + bb);
        }
      }
    } else {
      // MODE 2: u = exp(logit); per-column sums over this tile's 128 rows
#pragma unroll
      for (int fn = 0; fn < 4; ++fn) {
        int col = wc * 64 + fn * 16 + lr;
        float bb = bias[n0 + col];
        float S = 0.f;
#pragma unroll
        for (int fm = 0; fm < 4; ++fm) {
          int row = wr * 64 + fm * 16 + rq * 4;
#pragma unroll
          for (int jj = 0; jj < 4; ++jj) {
            float u = __expf(acc[fm][fn][jj] + bb);
            S += u;
            Cs[(row + jj) * 136 + col] = f2bf(u);
          }
        }
        S += __shfl_xor(S, 16);
        S += __shfl_xor(S, 32);
        if (rq == 0) sf2[wr * 128 + col] = S;
      }
    }
    __syncthreads();
    if (MODE == 2 && tid < 128) {
      float S = sf2[tid] + sf2[128 + tid];
      psum[(size_t)(m0 >> 7) * (128 << NBL2) + n0 + tid] = S;
    }
    unsigned short* Yb = (unsigned short*)Yv + (size_t)(n0 >> 9) * YHALF;
    const int nc = n0 & 511;
#pragma unroll
    for (int i = 0; i < 8; ++i) {
      int idx = tid + i * 256;     // 0..2047
      int row = idx >> 4, g = idx & 15;
      *(uint4*)(Yb + (size_t)(m0 + row) * 512 + nc + g * 8) =
          *(const uint4*)&Cs[row * 136 + g * 8];
    }
  } else {  // MODE 1: fp32 store
    float* Cf = (float*)smem;  // 64 x (stride 132)
    float* Yf = (float*)Yv;
#pragma unroll
    for (int p = 0; p < 2; ++p) {
      if (p) __syncthreads();
      if (wr == p) {
#pragma unroll
        for (int fn = 0; fn < 4; ++fn) {
          int col = wc * 64 + fn * 16 + lr;
          float bb = bias[n0 + col];
#pragma unroll
          for (int fm = 0; fm < 4; ++fm) {
            int lrow = fm * 16 + rq * 4;
#pragma unroll
            for (int jj = 0; jj < 4; ++jj)
              Cf[(lrow + jj) * 132 + col] = acc[fm][fn][jj] + bb;
          }
        }
      }
      __syncthreads();
#pragma unroll
      for (int i = 0; i < 8; ++i) {
        int idx = tid + i * 256;
        int row = idx >> 5, g = idx & 31;
        *(float4*)(Yf + (size_t)(m0 + p * 64 + row) * 512 + n0 + g * 4) =
            *(const float4*)&Cf[row * 132 + g * 4];
      }
    }
  }
}

// ---------------------------------------------------------------------------
// column-sum reduce over the 32 mtiles of each b -> 1/S ; both terms in one
// launch (grid 32: block>>4 selects term)
// ---------------------------------------------------------------------------
__global__ void colsum_reduce2(const float* __restrict__ psum,
                               float* __restrict__ colinv) {
  int t = blockIdx.x >> 4;
  int i = (blockIdx.x & 15) * 256 + threadIdx.x;  // b*512+f, 0..4095
  int b = i >> 9, f = i & 511;
  float S = 0.f;
#pragma unroll
  for (int c = 0; c < 32; ++c)
    S += psum[(size_t)(b * 32 + c) * 1024 + t * 512 + f];
  colinv[t * 4096 + i] = 1.f / S;
}

// ---------------------------------------------------------------------------
// kv partials via MFMA: C[d][ncol] = sum_s u[s][d]*B[s][ncol], B=[v*sin|v*cos]
// u is pre-exp'd bf16 (no front-end math). grid (8 s-chunks, 64 n), 256 thr.
// ---------------------------------------------------------------------------
__global__ __launch_bounds__(256) void kv_mfma(
    const unsigned short* __restrict__ Up, const unsigned short* __restrict__ Vpb,
    const float* __restrict__ sintab, const float* __restrict__ costab,
    float* __restrict__ kvpart) {
  __shared__ __align__(16) unsigned short kT[64 * 64];
  __shared__ __align__(16) unsigned short vT[128 * 64];
  const int tid = threadIdx.x;
  const int chunk = blockIdx.x;
  const int n = blockIdx.y;
  const int b = n >> 3, h = n & 7;
  const int lane = tid & 63;
  const int w = tid >> 6;
  const int lr = lane & 15;
  const int lk = (lane >> 4) * 8;
  const int sp = tid & 31;
  const int g = tid >> 5;
  f32x4 acc[4][2];
#pragma unroll
  for (int i = 0; i < 4; ++i) {
    acc[i][0] = (f32x4){0.f, 0.f, 0.f, 0.f};
    acc[i][1] = (f32x4){0.f, 0.f, 0.f, 0.f};
  }

  for (int st = 0; st < 8; ++st) {
    int sA = chunk * 512 + st * 64 + 2 * sp;
    const unsigned short* kp = Up + ((size_t)b * L_DIM + sA) * 512 + h * 64 + g * 8;
    uint4 ka = *(const uint4*)kp;
    uint4 kb = *(const uint4*)(kp + 512);
    int vr = ((sA >> 9) << 12) + ((sA & 511) << 3) + b;
    const unsigned short* vp = Vpb + (size_t)vr * 512 + h * 64 + g * 8;
    uint4 v0 = *(const uint4*)vp;
    uint4 v1 = *(const uint4*)(vp + 8 * 512);
    unsigned short ua[8], ub[8];
    *(uint4*)ua = ka;
    *(uint4*)ub = kb;
    float vA[8], vB[8];
    unpk8(v0, vA);
    unpk8(v1, vB);
    float sS = sintab[sA], sC = costab[sA];
    float tS = sintab[sA + 1], tC = costab[sA + 1];
    __syncthreads();  // previous iteration's MFMA LDS reads done
#pragma unroll
    for (int i = 0; i < 8; ++i) {
      int d = g * 8 + i;
      *(unsigned int*)&kT[swz64(d, 2 * sp)] =
          (unsigned int)ua[i] | ((unsigned int)ub[i] << 16);
    }
#pragma unroll
    for (int i = 0; i < 8; ++i) {
      int m = g * 8 + i;
      *(unsigned int*)&vT[swz64(m, 2 * sp)] = pkbf(vA[i] * sS, vB[i] * tS);
      *(unsigned int*)&vT[swz64(64 + m, 2 * sp)] = pkbf(vA[i] * sC, vB[i] * tC);
    }
    __syncthreads();
#pragma unroll
    for (int kk = 0; kk < 2; ++kk) {
      int ke = kk * 32 + lk;
      bf16x8 av[4], bv[2];
#pragma unroll
      for (int fm = 0; fm < 4; ++fm)
        av[fm] = *(const bf16x8*)&kT[swz64(fm * 16 + lr, ke)];
#pragma unroll
      for (int fn = 0; fn < 2; ++fn)
        bv[fn] = *(const bf16x8*)&vT[swz64(w * 32 + fn * 16 + lr, ke)];
#pragma unroll
      for (int fm = 0; fm < 4; ++fm)
#pragma unroll
        for (int fn = 0; fn < 2; ++fn)
          acc[fm][fn] = __builtin_amdgcn_mfma_f32_16x16x32_bf16(av[fm], bv[fn],
                                                                acc[fm][fn], 0, 0, 0);
    }
  }
  const int rq = lane >> 4;
#pragma unroll
  for (int fn = 0; fn < 2; ++fn) {
    int ncol = w * 32 + fn * 16 + lr;
    int m = ncol & 63;
    int ddbase = (ncol >> 6) * 64;
#pragma unroll
    for (int fm = 0; fm < 4; ++fm) {
#pragma unroll
      for (int jj = 0; jj < 4; ++jj) {
        int dd = ddbase + fm * 16 + rq * 4 + jj;
        kvpart[(((size_t)chunk * 64 + n) * 64 + m) * 128 + dd] = acc[fm][fn][jj];
      }
    }
  }
}

// reduce 8 chunks, normalize by 1/S, emit pre-swizzled bf16 kvT[n][m][dd']
__global__ void kv_reduce_swz(const float* __restrict__ part,
                              const float* __restrict__ colinv,
                              unsigned short* __restrict__ kvT) {
  int i = blockIdx.x * 256 + threadIdx.x;  // (n*64+m)*128+dd
  float s = 0.f;
#pragma unroll
  for (int c = 0; c < 8; ++c) s += part[(size_t)c * 524288 + i];
  int dd = i & 127;
  int m = (i >> 7) & 63;
  int n = i >> 13;
  float sc = colinv[(n >> 3) * 512 + (n & 7) * 64 + (dd & 63)];
  int gg = dd >> 3;
  int e = ((gg & 8) | ((gg ^ m) & 7)) * 8 + (dd & 7);
  kvT[(size_t)(i >> 7) * 128 + e] = f2bf(s * sc);
}

// ---------------------------------------------------------------------------
// Fused out pass, both terms (R8 known-good: vectorized Q loads, softmax via
// 8-lane-group shfl reduce, 1/sum folded into sin/cos scale).
// ---------------------------------------------------------------------------
__global__ __launch_bounds__(256) void out_fused(
    const unsigned short* __restrict__ Qp0, const unsigned short* __restrict__ Qp1,
    const unsigned short* __restrict__ kvT,
    const float* __restrict__ sintab, const float* __restrict__ costab,
    unsigned short* __restrict__ Yb) {
  __shared__ __align__(16) unsigned short q2s[64 * 128];
  __shared__ __align__(16) unsigned short kvs[2][64 * 128];
  const int tid = threadIdx.x;
  const int lc = blockIdx.x;
  const int n = blockIdx.y;
  const int b = n >> 3, h = n & 7;
  const int lane = tid & 63;
  const int w = tid >> 6;
  {
    const uint4* s0 = (const uint4*)(kvT + (size_t)n * 8192);
    const uint4* s1 = (const uint4*)(kvT + 524288 + (size_t)n * 8192);
    uint4* d0 = (uint4*)kvs[0];
    uint4* d1 = (uint4*)kvs[1];
#pragma unroll
    for (int i = 0; i < 4; ++i) {
      d0[tid + i * 256] = s0[tid + i * 256];
      d1[tid + i * 256] = s1[tid + i * 256];
    }
  }
  const int l0 = lc * 64;
  const int wr = w >> 1, wc = w & 1;
  const int lr = lane & 15;
  const int lk = (lane >> 4) * 8;
  const int rq = lane >> 4;
  f32x4 acc[2][2];
  acc[0][0] = acc[0][1] = acc[1][0] = acc[1][1] = (f32x4){0.f, 0.f, 0.f, 0.f};
#pragma unroll
  for (int t = 0; t < 2; ++t) {
    const unsigned short* Qp = t ? Qp1 : Qp0;
    if (t) __syncthreads();
#pragma unroll
    for (int i = 0; i < 2; ++i) {
      int idx = tid + i * 256;      // 0..511
      int row = idx >> 3;           // 0..63
      int g = idx & 7;
      uint4 q = *(const uint4*)(Qp + ((size_t)b * L_DIM + l0 + row) * 512 +
                                h * 64 + g * 8);
      float v[8];
      unpk8(q, v);
      float m8 = fmaxf(fmaxf(fmaxf(v[0], v[1]), fmaxf(v[2], v[3])),
                       fmaxf(fmaxf(v[4], v[5]), fmaxf(v[6], v[7])));
      m8 = fmaxf(m8, __shfl_xor(m8, 1));
      m8 = fmaxf(m8, __shfl_xor(m8, 2));
      m8 = fmaxf(m8, __shfl_xor(m8, 4));
      float e[8], s8;
#pragma unroll
      for (int k = 0; k < 8; ++k) e[k] = __expf(v[k] - m8);
      s8 = ((e[0] + e[1]) + (e[2] + e[3])) + ((e[4] + e[5]) + (e[6] + e[7]));
      s8 += __shfl_xor(s8, 1);
      s8 += __shfl_xor(s8, 2);
      s8 += __shfl_xor(s8, 4);
      float inv = 1.f / s8;
      int gl = l0 + row;
      float sn = sintab[gl] * inv;
      float cs = costab[gl] * inv;
      uint4 os, oc;
      os.x = pkbf(e[0] * sn, e[1] * sn); os.y = pkbf(e[2] * sn, e[3] * sn);
      os.z = pkbf(e[4] * sn, e[5] * sn); os.w = pkbf(e[6] * sn, e[7] * sn);
      oc.x = pkbf(e[0] * cs, e[1] * cs); oc.y = pkbf(e[2] * cs, e[3] * cs);
      oc.z = pkbf(e[4] * cs, e[5] * cs); oc.w = pkbf(e[6] * cs, e[7] * cs);
      *(uint4*)&q2s[swz128(row, g * 8)] = os;
      *(uint4*)&q2s[swz128(row, 64 + g * 8)] = oc;
    }
    __syncthreads();
#pragma unroll
    for (int ks = 0; ks < 4; ++ks) {
      int ke = ks * 32 + lk;
      bf16x8 av[2], bv[2];
#pragma unroll
      for (int fm = 0; fm < 2; ++fm)
        av[fm] = *(const bf16x8*)&q2s[swz128(wr * 32 + fm * 16 + lr, ke)];
#pragma unroll
      for (int fn = 0; fn < 2; ++fn)
        bv[fn] = *(const bf16x8*)&kvs[t][swz128(wc * 32 + fn * 16 + lr, ke)];
#pragma unroll
      for (int fm = 0; fm < 2; ++fm)
#pragma unroll
        for (int fn = 0; fn < 2; ++fn)
          acc[fm][fn] = __builtin_amdgcn_mfma_f32_16x16x32_bf16(av[fm], bv[fn],
                                                                acc[fm][fn], 0, 0, 0);
    }
  }
  __syncthreads();
  unsigned short* Os = q2s;  // 64 x (stride 72)
#pragma unroll
  for (int fn = 0; fn < 2; ++fn) {
    int col = wc * 32 + fn * 16 + lr;
#pragma unroll
    for (int fm = 0; fm < 2; ++fm) {
      int lrow = wr * 32 + fm * 16 + rq * 4;
#pragma unroll
      for (int jj = 0; jj < 4; ++jj)
        Os[(lrow + jj) * 72 + col] = f2bf(acc[fm][fn][jj]);
    }
  }
  __syncthreads();
#pragma unroll
  for (int i = 0; i < 2; ++i) {
    int idx = tid + i * 256;
    int row = idx >> 3, g = idx & 7;
    *(uint4*)(Yb + ((size_t)b * L_DIM + l0 + row) * 512 + h * 64 + g * 8) =
        *(const uint4*)&Os[row * 72 + g * 8];
  }
}

// ---------------------------------------------------------------------------
extern "C" void kernel_launch(void* const* d_in, const int* in_sizes, int n_in,
                              void* d_out, int out_size, void* d_ws, size_t ws_size,
                              hipStream_t stream) {
  const float* query = (const float*)d_in[0];
  const float* key   = (const float*)d_in[1];
  const float* value = (const float*)d_in[2];
  const float* Wq    = (const float*)d_in[3];
  const float* bq    = (const float*)d_in[4];
  const float* Wk    = (const float*)d_in[5];
  const float* bk    = (const float*)d_in[6];
  const float* Wv    = (const float*)d_in[7];
  const float* bv    = (const float*)d_in[8];
  const float* Wout  = (const float*)d_in[9];
  const float* bout  = (const float*)d_in[10];
  float* out = (float*)d_out;
  float* ws = (float*)d_ws;

  // workspace (fp32 slot units)
  const size_t F_PROJ0 = 0;                       // 32768x512 bf16 (t0)
  const size_t F_PROJ1 = F_PROJ0 + 8388608;       // 32768x512 bf16 (t1)
  const size_t F_VPB   = F_PROJ1 + 8388608;       // V proj bf16
  const size_t F_KVP   = F_VPB + 8388608;         // kv partials fp32 (aliases psum)
  const size_t F_KVT   = F_KVP + 4194304;         // kvT bf16, 2 terms
  const size_t F_XBUF  = F_KVT + 524288;          // bf16 input / attn-out (shared)
  const size_t F_WBF   = F_XBUF + 8388608;        // weights bf16
  const size_t F_CINV  = F_WBF + 786432;          // 1/S, 2 terms x 4096
  const size_t F_SIN   = F_CINV + 8192;
  const size_t F_COS   = F_SIN + 4096;
  const size_t TOTALF  = F_COS + 4096;
  if (ws_size < TOTALF * sizeof(float)) {
    fprintf(stderr, "kernel_launch: ws too small (%zu < %zu)\n", ws_size, TOTALF * 4);
    return;
  }
  unsigned short* proj0 = (unsigned short*)(ws + F_PROJ0);
  unsigned short* vpb   = (unsigned short*)(ws + F_VPB);
  float* kvpart = ws + F_KVP;
  unsigned short* kvT  = (unsigned short*)(ws + F_KVT);
  unsigned short* xbuf = (unsigned short*)(ws + F_XBUF);
  unsigned short* wbf  = (unsigned short*)(ws + F_WBF);
  float* cinv = ws + F_CINV;
  float* sintab = ws + F_SIN;
  float* costab = ws + F_COS;
  // psum aliases kvpart (1 MB of 16 MB region): consumed by colsum_reduce2
  // BEFORE any kv_mfma writes kvpart.
  float* psum = kvpart;
  const size_t WQ_O = 0, WK_O = 524288, WV_O = 1048576, WOUT_O = 1310720;

  // fused prologue: all weight conversions + sincos tables in one dispatch
  prep_kernel<<<784, 256, 0, stream>>>(Wq, Wk, Wv, Wout, wbf, sintab, costab);

  // V projection: value -> bf16 (xbuf) -> GEMM -> vpb
  convf2b<<<2048, 256, 0, stream>>>(value, xbuf, 2097152);
  gemm_xwt<0, 2><<<1024, 256, 0, stream>>>(xbuf, wbf + WV_O, bv, vpb, nullptr);

  // K projections (both terms, N=1024): u = exp(logit) + fused column sums
  convf2b<<<2048, 256, 0, stream>>>(key, xbuf, 2097152);
  gemm_xwt<2, 3><<<2048, 256, 0, stream>>>(xbuf, wbf + WK_O, bk, proj0, psum);
  colsum_reduce2<<<32, 256, 0, stream>>>(psum, cinv);
  for (int t = 0; t < T_DIM; ++t) {
    unsigned short* projt = proj0 + (size_t)t * YHALF;
    kv_mfma<<<dim3(8, 64), 256, 0, stream>>>(projt, vpb, sintab, costab, kvpart);
    kv_reduce_swz<<<2048, 256, 0, stream>>>(kvpart, cinv + t * 4096,
                                            kvT + (size_t)t * 524288);
  }

  // Q projections (both terms, N=1024): plain bf16 store
  convf2b<<<2048, 256, 0, stream>>>(query, xbuf, 2097152);
  gemm_xwt<0, 3><<<2048, 256, 0, stream>>>(xbuf, wbf + WQ_O, bq, proj0, nullptr);
  // fused output accumulation (q-softmax inside) -> xbuf
  out_fused<<<dim3(64, 64), 256, 0, stream>>>(proj0, proj0 + YHALF, kvT,
                                              sintab, costab, xbuf);
  // final projection: bf16 A, fp32 out
  gemm_xwt<1, 2><<<1024, 256, 0, stream>>>(xbuf, wbf + WOUT_O, bout, out, nullptr);
}